// Round 9
// baseline (252.640 us; speedup 1.0000x reference)
//
#include <hip/hip_runtime.h>
#include <math.h>

#define NN 50000
#define NE 800000
#define DM 128
#define NH 8
#define FF 512
#define NBLK 391    // ceil(50000/128)
#define NBLK64 782  // ceil(50000/64)

// merged prep kernel block ranges
#define PB_X    6250
#define PB_WT   192
#define PB_RP   196
#define PB_EMB  1563
#define PB_TOT  (PB_X + PB_WT + PB_RP + PB_EMB)

typedef __attribute__((ext_vector_type(8))) short bf16x8;
typedef __attribute__((ext_vector_type(4))) float f32x4;

__device__ __forceinline__ short f2bf(float f) {
    union { float f; unsigned u; } v; v.f = f;
    unsigned r = v.u + 0x7fff + ((v.u >> 16) & 1);
    return (short)(r >> 16);
}
__device__ __forceinline__ float bf2f(short s) {
    union { unsigned u; float f; } v; v.u = ((unsigned)(unsigned short)s) << 16;
    return v.f;
}
__device__ __forceinline__ float u2f(unsigned u) {
    union { unsigned u; float f; } v; v.u = u; return v.f;
}

// fast gelu (tanh form)
__device__ __forceinline__ float gelu_f(float x) {
    float u = x * (0.7978845608f + 0.0356774081f * x * x);
    float t = 1.f - 2.f / (__expf(2.f * u) + 1.f);
    return 0.5f * x * (1.f + t);
}

// ---------------------------------------------------------------------------
__device__ __forceinline__ void gload16(const void* g, void* l) {
    __builtin_amdgcn_global_load_lds(
        (const __attribute__((address_space(1))) void*)g,
        (__attribute__((address_space(3))) void*)l, 16, 0, 0);
}

// Stage 128x128 bf16 tile with XOR swizzle (inverse-swizzled global source +
// linear LDS dest; reads apply same XOR — rule #21).
__device__ __forceinline__ void stage_tile(const short* __restrict__ src, int row0,
                                           int maxrow, int ld, int col0,
                                           short* sm) {
    const int tid = threadIdx.x;
    const int w = tid >> 6, l = tid & 63;
    const int p = l & 15;
    #pragma unroll
    for (int j = 0; j < 8; ++j) {
        int lr = w * 32 + j * 4 + (l >> 4);
        int gr = row0 + lr; gr = gr > maxrow ? maxrow : gr;
        int s = p ^ (lr & 7);
        const short* g = src + (size_t)gr * ld + col0 + s * 8;
        gload16(g, sm + (w * 32 + j * 4) * 128);
    }
}

// Stage 64x128 bf16 tile, same swizzle (proven R5).
__device__ __forceinline__ void stage_tile64(const short* __restrict__ src, int row0,
                                             int maxrow, int ld, int col0,
                                             short* sm) {
    const int tid = threadIdx.x;
    const int w = tid >> 6, l = tid & 63;
    const int p = l & 15;
    #pragma unroll
    for (int j = 0; j < 4; ++j) {
        int lr = w * 16 + j * 4 + (l >> 4);
        int gr = row0 + lr; gr = gr > maxrow ? maxrow : gr;
        int s = p ^ (lr & 7);
        const short* g = src + (size_t)gr * ld + col0 + s * 8;
        gload16(g, sm + (w * 16 + j * 4) * 128);
    }
}

__device__ __forceinline__ bf16x8 frag_ld(const short* sm, int outer, int slot) {
    return *(const bf16x8*)(sm + outer * 128 + ((slot ^ (outer & 7)) << 3));
}

__device__ __forceinline__ void mfma_tile(const short* sA, const short* sB,
                                          int wm, int wn, int lane,
                                          f32x4 acc[4][4]) {
    const int l15 = lane & 15, l4 = lane >> 4;
    #pragma unroll
    for (int ks = 0; ks < 4; ++ks) {
        bf16x8 a[4], b[4];
        int slot = ks * 4 + l4;
        #pragma unroll
        for (int f = 0; f < 4; ++f) a[f] = frag_ld(sA, wm * 64 + f * 16 + l15, slot);
        #pragma unroll
        for (int f = 0; f < 4; ++f) b[f] = frag_ld(sB, wn * 64 + f * 16 + l15, slot);
        #pragma unroll
        for (int fm = 0; fm < 4; ++fm)
            #pragma unroll
            for (int fn = 0; fn < 4; ++fn)
                acc[fm][fn] = __builtin_amdgcn_mfma_f32_16x16x32_bf16(
                    a[fm], b[fn], acc[fm][fn], 0, 0, 0);
    }
}

// ---------------------------------------------------------------------------
// Merged prep: x->bf16 | 6 weight transposes | rowptr | embn materialization.
__global__ __launch_bounds__(256) void k_prep(
    const float* __restrict__ x, short* __restrict__ xb,
    const float* __restrict__ Wq, const float* __restrict__ Wk,
    const float* __restrict__ Wv, const float* __restrict__ Wo,
    const float* __restrict__ W1, const float* __restrict__ W2,
    short* __restrict__ wts,
    const int* __restrict__ row, int* __restrict__ rowptr,
    const int* __restrict__ db, const float* __restrict__ emb,
    float* __restrict__ embn)
{
    int bid = blockIdx.x;
    const int tid = threadIdx.x;

    if (bid < PB_X) {
        int i = bid * 256 + tid;
        if (i < NN * DM / 4) {
            float4 v = ((const float4*)x)[i];
            ((short4*)xb)[i] = make_short4(f2bf(v.x), f2bf(v.y), f2bf(v.z), f2bf(v.w));
        }
        return;
    }
    bid -= PB_X;
    if (bid < PB_WT) {
        const float* W; short* Wt; int K, N, bx, by;
        if (bid < 64) {
            int wsel = bid >> 4, rel = bid & 15;
            W = wsel == 0 ? Wq : wsel == 1 ? Wk : wsel == 2 ? Wv : Wo;
            Wt = wts + wsel * 16384; K = 128; N = 128; bx = rel & 3; by = rel >> 2;
        } else if (bid < 128) {
            int rel = bid - 64;
            W = W1; Wt = wts + 65536; K = 128; N = 512; bx = rel & 15; by = rel >> 4;
        } else {
            int rel = bid - 128;
            W = W2; Wt = wts + 131072; K = 512; N = 128; bx = rel & 3; by = rel >> 2;
        }
        __shared__ float t[32][33];
        int n0 = bx * 32, k0 = by * 32;
        int r = tid >> 3, c4 = (tid & 7) * 4;
        float4 v = *(const float4*)(W + (size_t)(k0 + r) * N + n0 + c4);
        t[r][c4 + 0] = v.x; t[r][c4 + 1] = v.y; t[r][c4 + 2] = v.z; t[r][c4 + 3] = v.w;
        __syncthreads();
        short4 o = make_short4(f2bf(t[c4 + 0][r]), f2bf(t[c4 + 1][r]),
                               f2bf(t[c4 + 2][r]), f2bf(t[c4 + 3][r]));
        *(short4*)(Wt + (size_t)(n0 + r) * K + k0 + c4) = o;
        return;
    }
    bid -= PB_WT;
    if (bid < PB_RP) {
        int n = bid * 256 + tid;
        if (n > NN) return;
        int lo = 0, hi = NE;
        while (lo < hi) {
            int mid = (lo + hi) >> 1;
            if (row[mid] < n) lo = mid + 1; else hi = mid;
        }
        rowptr[n] = lo;
        return;
    }
    bid -= PB_RP;
    {
        int i = bid * 256 + tid;
        if (i < NN * NH) embn[i] = emb[db[i >> 3] * NH + (i & 7)];
    }
}

// ---------------------------------------------------------------------------
__global__ __launch_bounds__(256) void k_gemm_qkv(
    const short* __restrict__ xb, const short* __restrict__ Wt,
    const float* __restrict__ bq, const float* __restrict__ bk,
    const float* __restrict__ bv,
    short* __restrict__ Qb, short* __restrict__ Kb, short* __restrict__ Vb)
{
    __shared__ short sm[2 * 16384];
    const int tid = threadIdx.x, lane = tid & 63, wid = tid >> 6;
    const int wm = wid >> 1, wn = wid & 1;
    const int r0 = blockIdx.x * 128;

    stage_tile(xb, r0, NN - 1, 128, 0, sm);
    #pragma unroll
    for (int m = 0; m < 3; ++m) {
        if (m) __syncthreads();
        stage_tile(Wt + m * 16384, 0, 127, 128, 0, sm + 16384);
        __syncthreads();
        f32x4 acc[4][4];
        #pragma unroll
        for (int i = 0; i < 4; ++i)
            #pragma unroll
            for (int j = 0; j < 4; ++j)
                acc[i][j] = (f32x4){0.f, 0.f, 0.f, 0.f};
        mfma_tile(sm, sm + 16384, wm, wn, lane, acc);

        const float* bias = m == 0 ? bq : (m == 1 ? bk : bv);
        short* out = m == 0 ? Qb : (m == 1 ? Kb : Vb);
        #pragma unroll
        for (int fn = 0; fn < 4; ++fn) {
            int col = wn * 64 + fn * 16 + (lane & 15);
            float bc = bias[col];
            #pragma unroll
            for (int fm = 0; fm < 4; ++fm) {
                int rowb = r0 + wm * 64 + fm * 16 + (lane >> 4) * 4;
                #pragma unroll
                for (int rr = 0; rr < 4; ++rr) {
                    int gr = rowb + rr;
                    if (gr < NN)
                        out[(size_t)gr * DM + col] = f2bf(acc[fm][fn][rr] + bc);
                }
            }
        }
    }
}

// ---------------------------------------------------------------------------
// Wave-per-node fused attention, 16-edge chunks, V preloaded alongside K.
__global__ __launch_bounds__(256) void k_attn_wave(
    const short* __restrict__ Qb, const short* __restrict__ Kb,
    const short* __restrict__ Vb, const int* __restrict__ col,
    const int* __restrict__ rowptr, const float* __restrict__ embn,
    short* __restrict__ aggb)
{
    const int lane = threadIdx.x & 63;
    const int n = blockIdx.x * 4 + (threadIdx.x >> 6);
    const int e0 = rowptr[n], e1 = rowptr[n + 1];
    const int s = lane >> 3, h = lane & 7;
    const int h2 = lane >> 3;

    float qf[16];
    {
        const bf16x8* qp = (const bf16x8*)(Qb + (size_t)n * DM + h * 16);
        bf16x8 q0 = qp[0], q1 = qp[1];
        #pragma unroll
        for (int j = 0; j < 8; ++j) { qf[j] = bf2f(q0[j]); qf[8 + j] = bf2f(q1[j]); }
    }
    const float embr = embn[(size_t)n * NH + h];

    float m = -INFINITY, l = 0.f, acc0 = 0.f, acc1 = 0.f;

    for (int c0 = e0; c0 < e1; c0 += 16) {
        int ea = c0 + s, eb = c0 + 8 + s;
        bool va = ea < e1, vb = eb < e1;
        int ca = col[va ? ea : e1 - 1];
        int cb = col[vb ? eb : e1 - 1];

        const bf16x8* kpa = (const bf16x8*)(Kb + (size_t)ca * DM + h * 16);
        const bf16x8* kpb = (const bf16x8*)(Kb + (size_t)cb * DM + h * 16);
        bf16x8 ka0 = kpa[0], ka1 = kpa[1];
        bf16x8 kb0 = kpb[0], kb1 = kpb[1];
        float ema = embn[(size_t)ca * NH + h];
        float emB = embn[(size_t)cb * NH + h];

        int nv = e1 - c0; nv = nv > 16 ? 16 : nv;
        unsigned vv[16];
        #pragma unroll
        for (int j = 0; j < 8; ++j) {
            int cj = __shfl(ca, j * 8);
            vv[j] = (j < nv) ? *(const unsigned*)(Vb + (size_t)cj * DM + lane * 2) : 0u;
        }
        #pragma unroll
        for (int j = 0; j < 8; ++j) {
            int cj = __shfl(cb, j * 8);
            vv[8 + j] = (8 + j < nv) ? *(const unsigned*)(Vb + (size_t)cj * DM + lane * 2) : 0u;
        }

        float da = 0.f, dbv = 0.f;
        #pragma unroll
        for (int j = 0; j < 8; ++j) {
            da  += qf[j] * bf2f(ka0[j]) + qf[8 + j] * bf2f(ka1[j]);
            dbv += qf[j] * bf2f(kb0[j]) + qf[8 + j] * bf2f(kb1[j]);
        }
        float sa = va ? da * 0.25f + embr + ema : -INFINITY;
        float sb = vb ? dbv * 0.25f + embr + emB : -INFINITY;

        float mc = fmaxf(sa, sb);
        mc = fmaxf(mc, __shfl_xor(mc, 8));
        mc = fmaxf(mc, __shfl_xor(mc, 16));
        mc = fmaxf(mc, __shfl_xor(mc, 32));
        float mn = fmaxf(m, mc);
        float f = __expf(m - mn);
        m = mn;
        float pa = __expf(sa - mn);
        float pb = __expf(sb - mn);
        float ps = pa + pb;
        ps += __shfl_xor(ps, 8);
        ps += __shfl_xor(ps, 16);
        ps += __shfl_xor(ps, 32);
        l = l * f + ps;

        float fr = __shfl(f, h2);
        acc0 *= fr; acc1 *= fr;
        #pragma unroll
        for (int j = 0; j < 8; ++j) {
            float pj = __shfl(pa, j * 8 + h2);
            acc0 += pj * u2f(vv[j] << 16);
            acc1 += pj * u2f(vv[j] & 0xffff0000u);
        }
        #pragma unroll
        for (int j = 0; j < 8; ++j) {
            float pj = __shfl(pb, j * 8 + h2);
            acc0 += pj * u2f(vv[8 + j] << 16);
            acc1 += pj * u2f(vv[8 + j] & 0xffff0000u);
        }
    }
    float la = __shfl(l, h2);
    la = fmaxf(la, 1e-12f);
    unsigned o = ((unsigned)(unsigned short)f2bf(acc0 / la)) |
                 (((unsigned)(unsigned short)f2bf(acc1 / la)) << 16);
    *(unsigned*)(aggb + (size_t)n * DM + lane * 2) = o;
}

// ---------------------------------------------------------------------------
// agg@Wo + bo + x -> LN1 -> hb (bf16)
__global__ __launch_bounds__(256) void k_gemm_ln1(
    const short* __restrict__ aggb, const short* __restrict__ Wot,
    const float* __restrict__ bo, const float* __restrict__ x,
    const float* __restrict__ g, const float* __restrict__ b,
    short* __restrict__ hb)
{
    __shared__ union { short ab[2 * 16384]; float hs[128 * 129]; } u;
    __shared__ float mu[128], rsd[128];
    const int tid = threadIdx.x, lane = tid & 63, wid = tid >> 6;
    const int wm = wid >> 1, wn = wid & 1;
    const int r0 = blockIdx.x * 128;

    stage_tile(aggb, r0, NN - 1, 128, 0, u.ab);
    stage_tile(Wot, 0, 127, 128, 0, u.ab + 16384);
    __syncthreads();

    f32x4 acc[4][4];
    #pragma unroll
    for (int i = 0; i < 4; ++i)
        #pragma unroll
        for (int j = 0; j < 4; ++j) acc[i][j] = (f32x4){0.f, 0.f, 0.f, 0.f};
    mfma_tile(u.ab, u.ab + 16384, wm, wn, lane, acc);
    __syncthreads();

    #pragma unroll
    for (int fn = 0; fn < 4; ++fn) {
        int col = wn * 64 + fn * 16 + (lane & 15);
        float bc = bo[col];
        #pragma unroll
        for (int fm = 0; fm < 4; ++fm) {
            int rowb = wm * 64 + fm * 16 + (lane >> 4) * 4;
            #pragma unroll
            for (int rr = 0; rr < 4; ++rr) {
                int r_ = rowb + rr, gr = r0 + r_;
                float xr = (gr < NN) ? x[(size_t)gr * DM + col] : 0.f;
                u.hs[r_ * 129 + col] = acc[fm][fn][rr] + bc + xr;
            }
        }
    }
    __syncthreads();

    {
        int rrow = tid >> 1, half = tid & 1;
        float s = 0.f, q = 0.f;
        #pragma unroll 8
        for (int c = 0; c < 64; ++c) {
            float v = u.hs[rrow * 129 + half * 64 + c];
            s += v; q += v * v;
        }
        s += __shfl_xor(s, 1);
        q += __shfl_xor(q, 1);
        float m = s * (1.f / DM);
        float var = q * (1.f / DM) - m * m;
        if (half == 0) { mu[rrow] = m; rsd[rrow] = rsqrtf(var + 1e-5f); }
    }
    __syncthreads();

    for (int i = 0; i < 64; ++i) {
        int idx = i * 256 + tid;
        int rrow = idx >> 7, c = idx & 127;
        int gr = r0 + rrow;
        if (gr < NN) {
            float v = (u.hs[rrow * 129 + c] - mu[rrow]) * rsd[rrow] * g[c] + b[c];
            hb[(size_t)gr * DM + c] = f2bf(v);
        }
    }
}

// ---------------------------------------------------------------------------
// FFN GEMM1: ffb[m, n0:n0+128] = gelu(hb @ W1t-chunk + b1). grid (391, 4).
// A staged in LDS (32 KB); W1t frags global->reg (L2-hot). One barrier.
__global__ __launch_bounds__(256) void k_gemm1(
    const short* __restrict__ hb, const short* __restrict__ Wt1,
    const float* __restrict__ b1, short* __restrict__ ffb)
{
    __shared__ short A[128 * 128];      // 32 KB
    const int tid = threadIdx.x, lane = tid & 63, wid = tid >> 6;
    const int wm = wid >> 1, wn = wid & 1;
    const int q = lane >> 4, r = lane & 15;
    const int r0 = blockIdx.x * 128;
    const int n0 = blockIdx.y * 128;

    stage_tile(hb, r0, NN - 1, 128, 0, A);
    __syncthreads();

    f32x4 acc[4][4];
    #pragma unroll
    for (int i = 0; i < 4; ++i)
        #pragma unroll
        for (int j = 0; j < 4; ++j) acc[i][j] = (f32x4){0.f, 0.f, 0.f, 0.f};

    #pragma unroll
    for (int ks = 0; ks < 4; ++ks) {
        int slot = ks * 4 + q;
        bf16x8 af[4], wf[4];
        #pragma unroll
        for (int fm = 0; fm < 4; ++fm)
            af[fm] = frag_ld(A, wm * 64 + fm * 16 + r, slot);
        #pragma unroll
        for (int fn = 0; fn < 4; ++fn)
            wf[fn] = *(const bf16x8*)(Wt1 +
                (size_t)(n0 + wn * 64 + fn * 16 + r) * DM + slot * 8);
        #pragma unroll
        for (int fm = 0; fm < 4; ++fm)
            #pragma unroll
            for (int fn = 0; fn < 4; ++fn)
                acc[fm][fn] = __builtin_amdgcn_mfma_f32_16x16x32_bf16(
                    af[fm], wf[fn], acc[fm][fn], 0, 0, 0);
    }

    #pragma unroll
    for (int fn = 0; fn < 4; ++fn) {
        int colg = n0 + wn * 64 + fn * 16 + r;
        float bc = b1[colg];
        #pragma unroll
        for (int fm = 0; fm < 4; ++fm) {
            int rowb = r0 + wm * 64 + fm * 16 + q * 4;
            #pragma unroll
            for (int rr = 0; rr < 4; ++rr) {
                int gr = rowb + rr;
                if (gr < NN)
                    ffb[(size_t)gr * FF + colg] = f2bf(gelu_f(acc[fm][fn][rr] + bc));
            }
        }
    }
}

// ---------------------------------------------------------------------------
// FFN GEMM2 + LN2: out = LN2(ffb @ W2t + b2 + hb). BM=64, grid 782.
// A chunks staged (16 KB); W2t global->reg; LN2 epilogue in registers.
__global__ __launch_bounds__(256) void k_gemm2_ln2(
    const short* __restrict__ ffb, const short* __restrict__ Wt2,
    const float* __restrict__ b2, const short* __restrict__ hb,
    const float* __restrict__ g, const float* __restrict__ bb,
    float* __restrict__ out)
{
    __shared__ short A[64 * 128];       // 16 KB
    __shared__ float2 rowstat[2][64];   // 1 KB
    const int tid = threadIdx.x, lane = tid & 63, wid = tid >> 6;
    const int wm = wid >> 1, wn = wid & 1;
    const int q = lane >> 4, r = lane & 15;
    const int r0 = blockIdx.x * 64;

    f32x4 acc[2][4];
    #pragma unroll
    for (int i = 0; i < 2; ++i)
        #pragma unroll
        for (int j = 0; j < 4; ++j) acc[i][j] = (f32x4){0.f, 0.f, 0.f, 0.f};

    for (int kc = 0; kc < 4; ++kc) {
        if (kc) __syncthreads();         // previous chunk's reads done
        stage_tile64(ffb, r0, NN - 1, FF, kc * 128, A);
        __syncthreads();                 // chunk staged

        #pragma unroll
        for (int ks = 0; ks < 4; ++ks) {
            int slot = ks * 4 + q;
            bf16x8 af[2], wf[4];
            #pragma unroll
            for (int fm = 0; fm < 2; ++fm)
                af[fm] = frag_ld(A, wm * 32 + fm * 16 + r, slot);
            #pragma unroll
            for (int fn = 0; fn < 4; ++fn)
                wf[fn] = *(const bf16x8*)(Wt2 +
                    (size_t)(wn * 64 + fn * 16 + r) * FF + kc * 128 + slot * 8);
            #pragma unroll
            for (int fm = 0; fm < 2; ++fm)
                #pragma unroll
                for (int fn = 0; fn < 4; ++fn)
                    acc[fm][fn] = __builtin_amdgcn_mfma_f32_16x16x32_bf16(
                        af[fm], wf[fn], acc[fm][fn], 0, 0, 0);
        }
    }

    // epilogue: val = acc + b2 + residual(hb); LN2 in registers.
    float b2c[4];
    #pragma unroll
    for (int fn = 0; fn < 4; ++fn) b2c[fn] = b2[wn * 64 + fn * 16 + r];

    float srow[2][4], qrow[2][4];
    #pragma unroll
    for (int fm = 0; fm < 2; ++fm) {
        #pragma unroll
        for (int rr = 0; rr < 4; ++rr) {
            int ml = wm * 32 + fm * 16 + q * 4 + rr;
            int gr = r0 + ml;
            int cr = gr < NN ? gr : NN - 1;
            float s = 0.f, ss = 0.f;
            #pragma unroll
            for (int fn = 0; fn < 4; ++fn) {
                int colc = wn * 64 + fn * 16 + r;
                float hr = bf2f(hb[(size_t)cr * DM + colc]);
                float v = acc[fm][fn][rr] + b2c[fn] + hr;
                acc[fm][fn][rr] = v;
                s += v; ss += v * v;
            }
            s  += __shfl_xor(s, 1);  ss += __shfl_xor(ss, 1);
            s  += __shfl_xor(s, 2);  ss += __shfl_xor(ss, 2);
            s  += __shfl_xor(s, 4);  ss += __shfl_xor(ss, 4);
            s  += __shfl_xor(s, 8);  ss += __shfl_xor(ss, 8);
            srow[fm][rr] = s; qrow[fm][rr] = ss;
        }
    }
    if (r == 0) {
        #pragma unroll
        for (int fm = 0; fm < 2; ++fm)
            #pragma unroll
            for (int rr = 0; rr < 4; ++rr)
                rowstat[wn][wm * 32 + fm * 16 + q * 4 + rr] =
                    make_float2(srow[fm][rr], qrow[fm][rr]);
    }
    __syncthreads();

    #pragma unroll
    for (int fm = 0; fm < 2; ++fm) {
        #pragma unroll
        for (int rr = 0; rr < 4; ++rr) {
            int ml = wm * 32 + fm * 16 + q * 4 + rr;
            int gr = r0 + ml;
            float2 a0 = rowstat[0][ml], a1 = rowstat[1][ml];
            float s = a0.x + a1.x, ss = a0.y + a1.y;
            float mu = s * (1.f / DM);
            float var = ss * (1.f / DM) - mu * mu;
            float rs = rsqrtf(var + 1e-5f);
            if (gr < NN) {
                #pragma unroll
                for (int fn = 0; fn < 4; ++fn) {
                    int colc = wn * 64 + fn * 16 + r;
                    out[(size_t)gr * DM + colc] =
                        (acc[fm][fn][rr] - mu) * rs * g[colc] + bb[colc];
                }
            }
        }
    }
}

// ---------------------------------------------------------------------------
extern "C" void kernel_launch(void* const* d_in, const int* in_sizes, int n_in,
                              void* d_out, int out_size, void* d_ws, size_t ws_size,
                              hipStream_t stream) {
    const float* x   = (const float*)d_in[0];
    const int* row   = (const int*)d_in[1];
    const int* col   = (const int*)d_in[2];
    const int* db    = (const int*)d_in[3];
    const float* Wq  = (const float*)d_in[4];
    const float* bq  = (const float*)d_in[5];
    const float* Wk  = (const float*)d_in[6];
    const float* bk  = (const float*)d_in[7];
    const float* Wv  = (const float*)d_in[8];
    const float* bv  = (const float*)d_in[9];
    const float* Wo  = (const float*)d_in[10];
    const float* bo  = (const float*)d_in[11];
    const float* emb = (const float*)d_in[12];
    const float* g1  = (const float*)d_in[13];
    const float* b1n = (const float*)d_in[14];
    const float* g2  = (const float*)d_in[15];
    const float* b2n = (const float*)d_in[16];
    const float* W1  = (const float*)d_in[17];
    const float* b1  = (const float*)d_in[18];
    const float* W2  = (const float*)d_in[19];
    const float* b2  = (const float*)d_in[20];

    char* W = (char*)d_ws;
    float* embn   = (float*)(W + 0);             // 1.6 MB
    short* ffb    = (short*)(W + 12800000);      // 51.2 MB: 12.8M..64M
                                                 // (overlays aggb/xb/Qb, all
                                                 //  dead by the time gemm1 runs)
    short* aggb   = (short*)(W + 25600000);
    short* xb     = (short*)(W + 38400000);
    short* Qb     = (short*)(W + 51200000);
    short* Kb     = (short*)(W + 64000000);
    short* Vb     = (short*)(W + 76800000);
    short* hb     = (short*)(W + 76800000);      // overlay (Vb dead after attn)
    short* wts    = (short*)(W + 89600000);
    int* rowptr   = (int*)(W + 89993216);

    k_prep<<<PB_TOT, 256, 0, stream>>>(x, xb, Wq, Wk, Wv, Wo, W1, W2, wts,
                                       row, rowptr, db, emb, embn);
    k_gemm_qkv<<<NBLK, 256, 0, stream>>>(xb, wts, bq, bk, bv, Qb, Kb, Vb);
    k_attn_wave<<<NN / 4, 256, 0, stream>>>(Qb, Kb, Vb, col, rowptr, embn, aggb);
    k_gemm_ln1<<<NBLK, 256, 0, stream>>>(aggb, wts + 49152, bo, x, g1, b1n, hb);
    k_gemm1<<<dim3(NBLK, 4), 256, 0, stream>>>(hb, wts + 65536, b1, ffb);
    k_gemm2_ln2<<<NBLK64, 256, 0, stream>>>(ffb, wts + 131072, b2, hb,
                                            g2, b2n, (float*)d_out);
}

// Round 10
// 218.991 us; speedup vs baseline: 1.1537x; 1.1537x over previous
//
#include <hip/hip_runtime.h>
#include <math.h>

#define NN 50000
#define NE 800000
#define DM 128
#define NH 8
#define FF 512
#define NBLK 391    // ceil(50000/128)
#define NBLK64 782  // ceil(50000/64)

// merged prep kernel block ranges
#define PB_X    6250          // x->bf16 blocks
#define PB_WT   192           // weight transpose blocks
#define PB_RP   196           // rowptr blocks
#define PB_EMB  1563          // embn blocks
#define PB_TOT  (PB_X + PB_WT + PB_RP + PB_EMB)

typedef __attribute__((ext_vector_type(8))) short bf16x8;
typedef __attribute__((ext_vector_type(4))) float f32x4;

__device__ __forceinline__ short f2bf(float f) {
    union { float f; unsigned u; } v; v.f = f;
    unsigned r = v.u + 0x7fff + ((v.u >> 16) & 1);
    return (short)(r >> 16);
}
__device__ __forceinline__ float bf2f(short s) {
    union { unsigned u; float f; } v; v.u = ((unsigned)(unsigned short)s) << 16;
    return v.f;
}
__device__ __forceinline__ float u2f(unsigned u) {
    union { unsigned u; float f; } v; v.u = u; return v.f;
}

// fast gelu (tanh form; |err|~2e-4 in our ff range, ~1e-4 after W2)
__device__ __forceinline__ float gelu_f(float x) {
    float u = x * (0.7978845608f + 0.0356774081f * x * x);
    float t = 1.f - 2.f / (__expf(2.f * u) + 1.f);
    return 0.5f * x * (1.f + t);
}

// ---------------------------------------------------------------------------
__device__ __forceinline__ void gload16(const void* g, void* l) {
    __builtin_amdgcn_global_load_lds(
        (const __attribute__((address_space(1))) void*)g,
        (__attribute__((address_space(3))) void*)l, 16, 0, 0);
}

// Stage 128x128 bf16 tile with XOR swizzle (inverse-swizzled global source +
// linear LDS dest; reads apply same XOR — rule #21).
__device__ __forceinline__ void stage_tile(const short* __restrict__ src, int row0,
                                           int maxrow, int ld, int col0,
                                           short* sm) {
    const int tid = threadIdx.x;
    const int w = tid >> 6, l = tid & 63;
    const int p = l & 15;
    #pragma unroll
    for (int j = 0; j < 8; ++j) {
        int lr = w * 32 + j * 4 + (l >> 4);
        int gr = row0 + lr; gr = gr > maxrow ? maxrow : gr;
        int s = p ^ (lr & 7);
        const short* g = src + (size_t)gr * ld + col0 + s * 8;
        gload16(g, sm + (w * 32 + j * 4) * 128);
    }
}

// Stage 64x128 bf16 tile, same swizzle.
__device__ __forceinline__ void stage_tile64(const short* __restrict__ src, int row0,
                                             int maxrow, int ld, int col0,
                                             short* sm) {
    const int tid = threadIdx.x;
    const int w = tid >> 6, l = tid & 63;
    const int p = l & 15;
    #pragma unroll
    for (int j = 0; j < 4; ++j) {
        int lr = w * 16 + j * 4 + (l >> 4);
        int gr = row0 + lr; gr = gr > maxrow ? maxrow : gr;
        int s = p ^ (lr & 7);
        const short* g = src + (size_t)gr * ld + col0 + s * 8;
        gload16(g, sm + (w * 16 + j * 4) * 128);
    }
}

__device__ __forceinline__ bf16x8 frag_ld(const short* sm, int outer, int slot) {
    return *(const bf16x8*)(sm + outer * 128 + ((slot ^ (outer & 7)) << 3));
}

__device__ __forceinline__ void mfma_tile(const short* sA, const short* sB,
                                          int wm, int wn, int lane,
                                          f32x4 acc[4][4]) {
    const int l15 = lane & 15, l4 = lane >> 4;
    #pragma unroll
    for (int ks = 0; ks < 4; ++ks) {
        bf16x8 a[4], b[4];
        int slot = ks * 4 + l4;
        #pragma unroll
        for (int f = 0; f < 4; ++f) a[f] = frag_ld(sA, wm * 64 + f * 16 + l15, slot);
        #pragma unroll
        for (int f = 0; f < 4; ++f) b[f] = frag_ld(sB, wn * 64 + f * 16 + l15, slot);
        #pragma unroll
        for (int fm = 0; fm < 4; ++fm)
            #pragma unroll
            for (int fn = 0; fn < 4; ++fn)
                acc[fm][fn] = __builtin_amdgcn_mfma_f32_16x16x32_bf16(
                    a[fm], b[fn], acc[fm][fn], 0, 0, 0);
    }
}

// 64x128x128: 4 waves 2x2, each 32m x 64n
__device__ __forceinline__ void mfma_tile64(const short* sA, const short* sB,
                                            int wm, int wn, int lane,
                                            f32x4 acc[2][4]) {
    const int l15 = lane & 15, l4 = lane >> 4;
    #pragma unroll
    for (int ks = 0; ks < 4; ++ks) {
        bf16x8 a[2], b[4];
        int slot = ks * 4 + l4;
        #pragma unroll
        for (int f = 0; f < 2; ++f) a[f] = frag_ld(sA, wm * 32 + f * 16 + l15, slot);
        #pragma unroll
        for (int f = 0; f < 4; ++f) b[f] = frag_ld(sB, wn * 64 + f * 16 + l15, slot);
        #pragma unroll
        for (int fm = 0; fm < 2; ++fm)
            #pragma unroll
            for (int fn = 0; fn < 4; ++fn)
                acc[fm][fn] = __builtin_amdgcn_mfma_f32_16x16x32_bf16(
                    a[fm], b[fn], acc[fm][fn], 0, 0, 0);
    }
}

// ---------------------------------------------------------------------------
// Merged prep: x->bf16 | 6 weight transposes | rowptr | embn materialization.
__global__ __launch_bounds__(256) void k_prep(
    const float* __restrict__ x, short* __restrict__ xb,
    const float* __restrict__ Wq, const float* __restrict__ Wk,
    const float* __restrict__ Wv, const float* __restrict__ Wo,
    const float* __restrict__ W1, const float* __restrict__ W2,
    short* __restrict__ wts,
    const int* __restrict__ row, int* __restrict__ rowptr,
    const int* __restrict__ db, const float* __restrict__ emb,
    float* __restrict__ embn)
{
    int bid = blockIdx.x;
    const int tid = threadIdx.x;

    if (bid < PB_X) {
        int i = bid * 256 + tid;
        if (i < NN * DM / 4) {
            float4 v = ((const float4*)x)[i];
            ((short4*)xb)[i] = make_short4(f2bf(v.x), f2bf(v.y), f2bf(v.z), f2bf(v.w));
        }
        return;
    }
    bid -= PB_X;
    if (bid < PB_WT) {
        const float* W; short* Wt; int K, N, bx, by;
        if (bid < 64) {
            int wsel = bid >> 4, rel = bid & 15;
            W = wsel == 0 ? Wq : wsel == 1 ? Wk : wsel == 2 ? Wv : Wo;
            Wt = wts + wsel * 16384; K = 128; N = 128; bx = rel & 3; by = rel >> 2;
        } else if (bid < 128) {
            int rel = bid - 64;
            W = W1; Wt = wts + 65536; K = 128; N = 512; bx = rel & 15; by = rel >> 4;
        } else {
            int rel = bid - 128;
            W = W2; Wt = wts + 131072; K = 512; N = 128; bx = rel & 3; by = rel >> 2;
        }
        __shared__ float t[32][33];
        int n0 = bx * 32, k0 = by * 32;
        int r = tid >> 3, c4 = (tid & 7) * 4;
        float4 v = *(const float4*)(W + (size_t)(k0 + r) * N + n0 + c4);
        t[r][c4 + 0] = v.x; t[r][c4 + 1] = v.y; t[r][c4 + 2] = v.z; t[r][c4 + 3] = v.w;
        __syncthreads();
        short4 o = make_short4(f2bf(t[c4 + 0][r]), f2bf(t[c4 + 1][r]),
                               f2bf(t[c4 + 2][r]), f2bf(t[c4 + 3][r]));
        *(short4*)(Wt + (size_t)(n0 + r) * K + k0 + c4) = o;
        return;
    }
    bid -= PB_WT;
    if (bid < PB_RP) {
        int n = bid * 256 + tid;
        if (n > NN) return;
        int lo = 0, hi = NE;
        while (lo < hi) {
            int mid = (lo + hi) >> 1;
            if (row[mid] < n) lo = mid + 1; else hi = mid;
        }
        rowptr[n] = lo;
        return;
    }
    bid -= PB_RP;
    {
        int i = bid * 256 + tid;
        if (i < NN * NH) embn[i] = emb[db[i >> 3] * NH + (i & 7)];
    }
}

// ---------------------------------------------------------------------------
__global__ __launch_bounds__(256) void k_gemm_qkv(
    const short* __restrict__ xb, const short* __restrict__ Wt,
    const float* __restrict__ bq, const float* __restrict__ bk,
    const float* __restrict__ bv,
    short* __restrict__ Qb, short* __restrict__ Kb, short* __restrict__ Vb)
{
    __shared__ short sm[2 * 16384];
    const int tid = threadIdx.x, lane = tid & 63, wid = tid >> 6;
    const int wm = wid >> 1, wn = wid & 1;
    const int r0 = blockIdx.x * 128;

    stage_tile(xb, r0, NN - 1, 128, 0, sm);
    #pragma unroll
    for (int m = 0; m < 3; ++m) {
        if (m) __syncthreads();
        stage_tile(Wt + m * 16384, 0, 127, 128, 0, sm + 16384);
        __syncthreads();
        f32x4 acc[4][4];
        #pragma unroll
        for (int i = 0; i < 4; ++i)
            #pragma unroll
            for (int j = 0; j < 4; ++j)
                acc[i][j] = (f32x4){0.f, 0.f, 0.f, 0.f};
        mfma_tile(sm, sm + 16384, wm, wn, lane, acc);

        const float* bias = m == 0 ? bq : (m == 1 ? bk : bv);
        short* out = m == 0 ? Qb : (m == 1 ? Kb : Vb);
        #pragma unroll
        for (int fn = 0; fn < 4; ++fn) {
            int col = wn * 64 + fn * 16 + (lane & 15);
            float bc = bias[col];
            #pragma unroll
            for (int fm = 0; fm < 4; ++fm) {
                int rowb = r0 + wm * 64 + fm * 16 + (lane >> 4) * 4;
                #pragma unroll
                for (int rr = 0; rr < 4; ++rr) {
                    int gr = rowb + rr;
                    if (gr < NN)
                        out[(size_t)gr * DM + col] = f2bf(acc[fm][fn][rr] + bc);
                }
            }
        }
    }
}

// ---------------------------------------------------------------------------
// Wave-per-node fused attention, 16-edge chunks, V preloaded alongside K,
// defer-rescale (skip online-softmax rescale when chunk max doesn't grow).
__global__ __launch_bounds__(256) void k_attn_wave(
    const short* __restrict__ Qb, const short* __restrict__ Kb,
    const short* __restrict__ Vb, const int* __restrict__ col,
    const int* __restrict__ rowptr, const float* __restrict__ embn,
    short* __restrict__ aggb)
{
    const int lane = threadIdx.x & 63;
    const int n = blockIdx.x * 4 + (threadIdx.x >> 6);
    const int e0 = rowptr[n], e1 = rowptr[n + 1];
    const int s = lane >> 3, h = lane & 7;
    const int h2 = lane >> 3;

    float qf[16];
    {
        const bf16x8* qp = (const bf16x8*)(Qb + (size_t)n * DM + h * 16);
        bf16x8 q0 = qp[0], q1 = qp[1];
        #pragma unroll
        for (int j = 0; j < 8; ++j) { qf[j] = bf2f(q0[j]); qf[8 + j] = bf2f(q1[j]); }
    }
    const float embr = embn[(size_t)n * NH + h];

    float m = -INFINITY, l = 0.f, acc0 = 0.f, acc1 = 0.f;

    for (int c0 = e0; c0 < e1; c0 += 16) {
        int ea = c0 + s, eb = c0 + 8 + s;
        bool va = ea < e1, vb = eb < e1;
        int ca = col[va ? ea : e1 - 1];
        int cb = col[vb ? eb : e1 - 1];

        const bf16x8* kpa = (const bf16x8*)(Kb + (size_t)ca * DM + h * 16);
        const bf16x8* kpb = (const bf16x8*)(Kb + (size_t)cb * DM + h * 16);
        bf16x8 ka0 = kpa[0], ka1 = kpa[1];
        bf16x8 kb0 = kpb[0], kb1 = kpb[1];
        float ema = embn[(size_t)ca * NH + h];
        float emB = embn[(size_t)cb * NH + h];

        int nv = e1 - c0; nv = nv > 16 ? 16 : nv;
        unsigned vv[16];
        #pragma unroll
        for (int j = 0; j < 8; ++j) {
            int cj = __shfl(ca, j * 8);
            vv[j] = (j < nv) ? *(const unsigned*)(Vb + (size_t)cj * DM + lane * 2) : 0u;
        }
        #pragma unroll
        for (int j = 0; j < 8; ++j) {
            int cj = __shfl(cb, j * 8);
            vv[8 + j] = (8 + j < nv) ? *(const unsigned*)(Vb + (size_t)cj * DM + lane * 2) : 0u;
        }

        float da = 0.f, dbv = 0.f;
        #pragma unroll
        for (int j = 0; j < 8; ++j) {
            da  += qf[j] * bf2f(ka0[j]) + qf[8 + j] * bf2f(ka1[j]);
            dbv += qf[j] * bf2f(kb0[j]) + qf[8 + j] * bf2f(kb1[j]);
        }
        float sa = va ? da * 0.25f + embr + ema : -INFINITY;
        float sb = vb ? dbv * 0.25f + embr + emB : -INFINITY;

        // per-head chunk max
        float mc = fmaxf(sa, sb);
        mc = fmaxf(mc, __shfl_xor(mc, 8));
        mc = fmaxf(mc, __shfl_xor(mc, 16));
        mc = fmaxf(mc, __shfl_xor(mc, 32));

        // defer-rescale (T13): skip rescale when no head's max grows by >8.
        // p then bounded by e^8 — fine in f32 accum.
        float f = 1.f;
        bool grow = !__all(mc <= m + 8.f);
        if (grow) {
            float mn = fmaxf(m, mc);
            f = __expf(m - mn);          // exp(-inf)=0 first chunk
            m = mn;
        }
        float pa = __expf(sa - m);
        float pb = __expf(sb - m);
        float ps = pa + pb;
        ps += __shfl_xor(ps, 8);
        ps += __shfl_xor(ps, 16);
        ps += __shfl_xor(ps, 32);
        if (grow) {
            l *= f;
            float fr = __shfl(f, h2);
            acc0 *= fr; acc1 *= fr;
        }
        l += ps;

        #pragma unroll
        for (int j = 0; j < 8; ++j) {
            float pj = __shfl(pa, j * 8 + h2);
            acc0 += pj * u2f(vv[j] << 16);
            acc1 += pj * u2f(vv[j] & 0xffff0000u);
        }
        #pragma unroll
        for (int j = 0; j < 8; ++j) {
            float pj = __shfl(pb, j * 8 + h2);
            acc0 += pj * u2f(vv[8 + j] << 16);
            acc1 += pj * u2f(vv[8 + j] & 0xffff0000u);
        }
    }
    float la = __shfl(l, h2);
    la = fmaxf(la, 1e-12f);
    unsigned o = ((unsigned)(unsigned short)f2bf(acc0 / la)) |
                 (((unsigned)(unsigned short)f2bf(acc1 / la)) << 16);
    *(unsigned*)(aggb + (size_t)n * DM + lane * 2) = o;
}

// ---------------------------------------------------------------------------
// agg@Wo + bo + x -> LN1 -> h (f32) and hb (bf16)
__global__ __launch_bounds__(256) void k_gemm_ln1(
    const short* __restrict__ aggb, const short* __restrict__ Wot,
    const float* __restrict__ bo, const float* __restrict__ x,
    const float* __restrict__ g, const float* __restrict__ b,
    float* __restrict__ h, short* __restrict__ hb)
{
    __shared__ union { short ab[2 * 16384]; float hs[128 * 129]; } u;
    __shared__ float mu[128], rsd[128];
    const int tid = threadIdx.x, lane = tid & 63, wid = tid >> 6;
    const int wm = wid >> 1, wn = wid & 1;
    const int r0 = blockIdx.x * 128;

    stage_tile(aggb, r0, NN - 1, 128, 0, u.ab);
    stage_tile(Wot, 0, 127, 128, 0, u.ab + 16384);
    __syncthreads();

    f32x4 acc[4][4];
    #pragma unroll
    for (int i = 0; i < 4; ++i)
        #pragma unroll
        for (int j = 0; j < 4; ++j) acc[i][j] = (f32x4){0.f, 0.f, 0.f, 0.f};
    mfma_tile(u.ab, u.ab + 16384, wm, wn, lane, acc);
    __syncthreads();

    #pragma unroll
    for (int fn = 0; fn < 4; ++fn) {
        int col = wn * 64 + fn * 16 + (lane & 15);
        float bc = bo[col];
        #pragma unroll
        for (int fm = 0; fm < 4; ++fm) {
            int rowb = wm * 64 + fm * 16 + (lane >> 4) * 4;
            #pragma unroll
            for (int rr = 0; rr < 4; ++rr) {
                int r_ = rowb + rr, gr = r0 + r_;
                float xr = (gr < NN) ? x[(size_t)gr * DM + col] : 0.f;
                u.hs[r_ * 129 + col] = acc[fm][fn][rr] + bc + xr;
            }
        }
    }
    __syncthreads();

    {
        int rrow = tid >> 1, half = tid & 1;
        float s = 0.f, q = 0.f;
        #pragma unroll 8
        for (int c = 0; c < 64; ++c) {
            float v = u.hs[rrow * 129 + half * 64 + c];
            s += v; q += v * v;
        }
        s += __shfl_xor(s, 1);
        q += __shfl_xor(q, 1);
        float m = s * (1.f / DM);
        float var = q * (1.f / DM) - m * m;
        if (half == 0) { mu[rrow] = m; rsd[rrow] = rsqrtf(var + 1e-5f); }
    }
    __syncthreads();

    for (int i = 0; i < 64; ++i) {
        int idx = i * 256 + tid;
        int rrow = idx >> 7, c = idx & 127;
        int gr = r0 + rrow;
        if (gr < NN) {
            float v = (u.hs[rrow * 129 + c] - mu[rrow]) * rsd[rrow] * g[c] + b[c];
            h[(size_t)gr * DM + c] = v;
            hb[(size_t)gr * DM + c] = f2bf(v);
        }
    }
}

// ---------------------------------------------------------------------------
// Fused FFN (R5 structure, best measured): gelu(hb@W1+b1)@W2 + b2 + h -> LN2.
// BM=64, 64KB dyn LDS: A[64x128] hb | B[128x128] weight chunk | C[64x128] ff.
__global__ __launch_bounds__(256) void k_ffn_fused(
    const short* __restrict__ hb, const short* __restrict__ Wt1,
    const float* __restrict__ b1, const short* __restrict__ Wt2,
    const float* __restrict__ b2, const float* __restrict__ h,
    const float* __restrict__ g, const float* __restrict__ bb,
    float* __restrict__ out)
{
    extern __shared__ char smraw[];
    short* A = (short*)smraw;          // 16 KB
    short* B = A + 8192;               // 32 KB
    short* C = B + 16384;              // 16 KB
    float* hs = (float*)smraw;         // overlay after gemms
    __shared__ float mu[64], rsd[64];

    const int tid = threadIdx.x, lane = tid & 63, wid = tid >> 6;
    const int wm = wid >> 1, wn = wid & 1;
    const int r0 = blockIdx.x * 64;

    f32x4 acc2[2][4];
    #pragma unroll
    for (int i = 0; i < 2; ++i)
        #pragma unroll
        for (int j = 0; j < 4; ++j) acc2[i][j] = (f32x4){0.f, 0.f, 0.f, 0.f};

    stage_tile64(hb, r0, NN - 1, 128, 0, A);

    for (int kc = 0; kc < 4; ++kc) {
        if (kc) __syncthreads();
        stage_tile(Wt1, kc * 128, FF - 1, 128, 0, B);
        __syncthreads();

        f32x4 accf[2][4];
        #pragma unroll
        for (int i = 0; i < 2; ++i)
            #pragma unroll
            for (int j = 0; j < 4; ++j) accf[i][j] = (f32x4){0.f, 0.f, 0.f, 0.f};
        mfma_tile64(A, B, wm, wn, lane, accf);

        #pragma unroll
        for (int fn = 0; fn < 4; ++fn) {
            int nloc = wn * 64 + fn * 16 + (lane & 15);
            float bc = b1[kc * 128 + nloc];
            int slot = nloc >> 3;
            #pragma unroll
            for (int fm = 0; fm < 2; ++fm) {
                int rowb = wm * 32 + fm * 16 + (lane >> 4) * 4;
                #pragma unroll
                for (int rr = 0; rr < 4; ++rr) {
                    int row = rowb + rr;
                    float v = gelu_f(accf[fm][fn][rr] + bc);
                    C[row * 128 + (((slot ^ (row & 7)) << 3) | (nloc & 7))] = f2bf(v);
                }
            }
        }
        __syncthreads();
        stage_tile(Wt2, 0, 127, FF, kc * 128, B);
        __syncthreads();
        mfma_tile64(C, B, wm, wn, lane, acc2);
    }
    __syncthreads();

    #pragma unroll
    for (int fn = 0; fn < 4; ++fn) {
        int col = wn * 64 + fn * 16 + (lane & 15);
        float bc = b2[col];
        #pragma unroll
        for (int fm = 0; fm < 2; ++fm) {
            int rowb = wm * 32 + fm * 16 + (lane >> 4) * 4;
            #pragma unroll
            for (int rr = 0; rr < 4; ++rr) {
                int r_ = rowb + rr, gr = r0 + r_;
                float hr = (gr < NN) ? h[(size_t)gr * DM + col] : 0.f;
                hs[r_ * 129 + col] = acc2[fm][fn][rr] + bc + hr;
            }
        }
    }
    __syncthreads();

    {
        int rrow = tid >> 2, q = tid & 3;
        float s = 0.f, qq = 0.f;
        #pragma unroll 8
        for (int c = 0; c < 32; ++c) {
            float v = hs[rrow * 129 + q * 32 + c];
            s += v; qq += v * v;
        }
        s += __shfl_xor(s, 1);  qq += __shfl_xor(qq, 1);
        s += __shfl_xor(s, 2);  qq += __shfl_xor(qq, 2);
        float m = s * (1.f / DM);
        float var = qq * (1.f / DM) - m * m;
        if (q == 0) { mu[rrow] = m; rsd[rrow] = rsqrtf(var + 1e-5f); }
    }
    __syncthreads();

    for (int i = 0; i < 32; ++i) {
        int idx = i * 256 + tid;
        int rrow = idx >> 7, c = idx & 127;
        int gr = r0 + rrow;
        if (gr < NN)
            out[(size_t)gr * DM + c] =
                (hs[rrow * 129 + c] - mu[rrow]) * rsd[rrow] * g[c] + bb[c];
    }
}

// ---------------------------------------------------------------------------
extern "C" void kernel_launch(void* const* d_in, const int* in_sizes, int n_in,
                              void* d_out, int out_size, void* d_ws, size_t ws_size,
                              hipStream_t stream) {
    const float* x   = (const float*)d_in[0];
    const int* row   = (const int*)d_in[1];
    const int* col   = (const int*)d_in[2];
    const int* db    = (const int*)d_in[3];
    const float* Wq  = (const float*)d_in[4];
    const float* bq  = (const float*)d_in[5];
    const float* Wk  = (const float*)d_in[6];
    const float* bk  = (const float*)d_in[7];
    const float* Wv  = (const float*)d_in[8];
    const float* bv  = (const float*)d_in[9];
    const float* Wo  = (const float*)d_in[10];
    const float* bo  = (const float*)d_in[11];
    const float* emb = (const float*)d_in[12];
    const float* g1  = (const float*)d_in[13];
    const float* b1n = (const float*)d_in[14];
    const float* g2  = (const float*)d_in[15];
    const float* b2n = (const float*)d_in[16];
    const float* W1  = (const float*)d_in[17];
    const float* b1  = (const float*)d_in[18];
    const float* W2  = (const float*)d_in[19];
    const float* b2  = (const float*)d_in[20];

    char* W = (char*)d_ws;
    float* embn   = (float*)(W + 0);             // 1.6 MB
    short* aggb   = (short*)(W + 25600000);
    short* xb     = (short*)(W + 38400000);
    short* Qb     = (short*)(W + 51200000);
    short* Kb     = (short*)(W + 64000000);
    float* h      = (float*)(W + 51200000);      // overlay (Qb/Kb dead)
    short* Vb     = (short*)(W + 76800000);
    short* hb     = (short*)(W + 76800000);      // overlay (Vb dead)
    short* wts    = (short*)(W + 89600000);
    int* rowptr   = (int*)(W + 89993216);

    k_prep<<<PB_TOT, 256, 0, stream>>>(x, xb, Wq, Wk, Wv, Wo, W1, W2, wts,
                                       row, rowptr, db, emb, embn);
    k_gemm_qkv<<<NBLK, 256, 0, stream>>>(xb, wts, bq, bk, bv, Qb, Kb, Vb);
    k_attn_wave<<<NN / 4, 256, 0, stream>>>(Qb, Kb, Vb, col, rowptr, embn, aggb);
    k_gemm_ln1<<<NBLK, 256, 0, stream>>>(aggb, wts + 49152, bo, x, g1, b1n, h, hb);
    k_ffn_fused<<<NBLK64, 256, 65536, stream>>>(hb, wts + 65536, b1,
                                                wts + 131072, b2, h, g2, b2n,
                                                (float*)d_out);
}

// Round 11
// 208.490 us; speedup vs baseline: 1.2118x; 1.0504x over previous
//
#include <hip/hip_runtime.h>
#include <math.h>

#define NN 50000
#define NE 800000
#define DM 128
#define NH 8
#define FF 512
#define NBLK 391    // ceil(50000/128)
#define NBLK64 782  // ceil(50000/64)

// merged prep kernel block ranges
#define PB_X    6250          // x->bf16 blocks
#define PB_WT   192           // weight transpose blocks
#define PB_RP   196           // rowptr blocks
#define PB_EMB  1563          // embn blocks
#define PB_TOT  (PB_X + PB_WT + PB_RP + PB_EMB)

typedef __attribute__((ext_vector_type(8))) short bf16x8;
typedef __attribute__((ext_vector_type(4))) float f32x4;
typedef __attribute__((ext_vector_type(2))) float f32x2;

__device__ __forceinline__ short f2bf(float f) {
    union { float f; unsigned u; } v; v.f = f;
    unsigned r = v.u + 0x7fff + ((v.u >> 16) & 1);
    return (short)(r >> 16);
}
__device__ __forceinline__ float bf2f(short s) {
    union { unsigned u; float f; } v; v.u = ((unsigned)(unsigned short)s) << 16;
    return v.f;
}
// fp8 e4m3 encode via HW cvt (RNE)
__device__ __forceinline__ unsigned char f2fp8(float f) {
    int p = __builtin_amdgcn_cvt_pk_fp8_f32(f, f, 0, false);
    return (unsigned char)(p & 0xff);
}

// fast gelu (tanh form; |err|~2e-4 in our ff range, ~1e-4 after W2)
__device__ __forceinline__ float gelu_f(float x) {
    float u = x * (0.7978845608f + 0.0356774081f * x * x);
    float t = 1.f - 2.f / (__expf(2.f * u) + 1.f);
    return 0.5f * x * (1.f + t);
}

// ---------------------------------------------------------------------------
__device__ __forceinline__ void gload16(const void* g, void* l) {
    __builtin_amdgcn_global_load_lds(
        (const __attribute__((address_space(1))) void*)g,
        (__attribute__((address_space(3))) void*)l, 16, 0, 0);
}

// Stage 128x128 bf16 tile with XOR swizzle (inverse-swizzled global source +
// linear LDS dest; reads apply same XOR — rule #21).
__device__ __forceinline__ void stage_tile(const short* __restrict__ src, int row0,
                                           int maxrow, int ld, int col0,
                                           short* sm) {
    const int tid = threadIdx.x;
    const int w = tid >> 6, l = tid & 63;
    const int p = l & 15;
    #pragma unroll
    for (int j = 0; j < 8; ++j) {
        int lr = w * 32 + j * 4 + (l >> 4);
        int gr = row0 + lr; gr = gr > maxrow ? maxrow : gr;
        int s = p ^ (lr & 7);
        const short* g = src + (size_t)gr * ld + col0 + s * 8;
        gload16(g, sm + (w * 32 + j * 4) * 128);
    }
}

// Stage 64x128 bf16 tile, same swizzle.
__device__ __forceinline__ void stage_tile64(const short* __restrict__ src, int row0,
                                             int maxrow, int ld, int col0,
                                             short* sm) {
    const int tid = threadIdx.x;
    const int w = tid >> 6, l = tid & 63;
    const int p = l & 15;
    #pragma unroll
    for (int j = 0; j < 4; ++j) {
        int lr = w * 16 + j * 4 + (l >> 4);
        int gr = row0 + lr; gr = gr > maxrow ? maxrow : gr;
        int s = p ^ (lr & 7);
        const short* g = src + (size_t)gr * ld + col0 + s * 8;
        gload16(g, sm + (w * 16 + j * 4) * 128);
    }
}

__device__ __forceinline__ bf16x8 frag_ld(const short* sm, int outer, int slot) {
    return *(const bf16x8*)(sm + outer * 128 + ((slot ^ (outer & 7)) << 3));
}

__device__ __forceinline__ void mfma_tile(const short* sA, const short* sB,
                                          int wm, int wn, int lane,
                                          f32x4 acc[4][4]) {
    const int l15 = lane & 15, l4 = lane >> 4;
    #pragma unroll
    for (int ks = 0; ks < 4; ++ks) {
        bf16x8 a[4], b[4];
        int slot = ks * 4 + l4;
        #pragma unroll
        for (int f = 0; f < 4; ++f) a[f] = frag_ld(sA, wm * 64 + f * 16 + l15, slot);
        #pragma unroll
        for (int f = 0; f < 4; ++f) b[f] = frag_ld(sB, wn * 64 + f * 16 + l15, slot);
        #pragma unroll
        for (int fm = 0; fm < 4; ++fm)
            #pragma unroll
            for (int fn = 0; fn < 4; ++fn)
                acc[fm][fn] = __builtin_amdgcn_mfma_f32_16x16x32_bf16(
                    a[fm], b[fn], acc[fm][fn], 0, 0, 0);
    }
}

// 64x128x128: 4 waves 2x2, each 32m x 64n
__device__ __forceinline__ void mfma_tile64(const short* sA, const short* sB,
                                            int wm, int wn, int lane,
                                            f32x4 acc[2][4]) {
    const int l15 = lane & 15, l4 = lane >> 4;
    #pragma unroll
    for (int ks = 0; ks < 4; ++ks) {
        bf16x8 a[2], b[4];
        int slot = ks * 4 + l4;
        #pragma unroll
        for (int f = 0; f < 2; ++f) a[f] = frag_ld(sA, wm * 32 + f * 16 + l15, slot);
        #pragma unroll
        for (int f = 0; f < 4; ++f) b[f] = frag_ld(sB, wn * 64 + f * 16 + l15, slot);
        #pragma unroll
        for (int fm = 0; fm < 2; ++fm)
            #pragma unroll
            for (int fn = 0; fn < 4; ++fn)
                acc[fm][fn] = __builtin_amdgcn_mfma_f32_16x16x32_bf16(
                    a[fm], b[fn], acc[fm][fn], 0, 0, 0);
    }
}

// ---------------------------------------------------------------------------
// Merged prep: x->bf16 | 6 weight transposes | rowptr | embn materialization.
__global__ __launch_bounds__(256) void k_prep(
    const float* __restrict__ x, short* __restrict__ xb,
    const float* __restrict__ Wq, const float* __restrict__ Wk,
    const float* __restrict__ Wv, const float* __restrict__ Wo,
    const float* __restrict__ W1, const float* __restrict__ W2,
    short* __restrict__ wts,
    const int* __restrict__ row, int* __restrict__ rowptr,
    const int* __restrict__ db, const float* __restrict__ emb,
    float* __restrict__ embn)
{
    int bid = blockIdx.x;
    const int tid = threadIdx.x;

    if (bid < PB_X) {
        int i = bid * 256 + tid;
        if (i < NN * DM / 4) {
            float4 v = ((const float4*)x)[i];
            ((short4*)xb)[i] = make_short4(f2bf(v.x), f2bf(v.y), f2bf(v.z), f2bf(v.w));
        }
        return;
    }
    bid -= PB_X;
    if (bid < PB_WT) {
        const float* W; short* Wt; int K, N, bx, by;
        if (bid < 64) {
            int wsel = bid >> 4, rel = bid & 15;
            W = wsel == 0 ? Wq : wsel == 1 ? Wk : wsel == 2 ? Wv : Wo;
            Wt = wts + wsel * 16384; K = 128; N = 128; bx = rel & 3; by = rel >> 2;
        } else if (bid < 128) {
            int rel = bid - 64;
            W = W1; Wt = wts + 65536; K = 128; N = 512; bx = rel & 15; by = rel >> 4;
        } else {
            int rel = bid - 128;
            W = W2; Wt = wts + 131072; K = 512; N = 128; bx = rel & 3; by = rel >> 2;
        }
        __shared__ float t[32][33];
        int n0 = bx * 32, k0 = by * 32;
        int r = tid >> 3, c4 = (tid & 7) * 4;
        float4 v = *(const float4*)(W + (size_t)(k0 + r) * N + n0 + c4);
        t[r][c4 + 0] = v.x; t[r][c4 + 1] = v.y; t[r][c4 + 2] = v.z; t[r][c4 + 3] = v.w;
        __syncthreads();
        short4 o = make_short4(f2bf(t[c4 + 0][r]), f2bf(t[c4 + 1][r]),
                               f2bf(t[c4 + 2][r]), f2bf(t[c4 + 3][r]));
        *(short4*)(Wt + (size_t)(n0 + r) * K + k0 + c4) = o;
        return;
    }
    bid -= PB_WT;
    if (bid < PB_RP) {
        int n = bid * 256 + tid;
        if (n > NN) return;
        int lo = 0, hi = NE;
        while (lo < hi) {
            int mid = (lo + hi) >> 1;
            if (row[mid] < n) lo = mid + 1; else hi = mid;
        }
        rowptr[n] = lo;
        return;
    }
    bid -= PB_RP;
    {
        int i = bid * 256 + tid;
        if (i < NN * NH) embn[i] = emb[db[i >> 3] * NH + (i & 7)];
    }
}

// ---------------------------------------------------------------------------
// QKV: Q out as bf16; K and V out as fp8 e4m3 (halves attn gather traffic).
__global__ __launch_bounds__(256) void k_gemm_qkv(
    const short* __restrict__ xb, const short* __restrict__ Wt,
    const float* __restrict__ bq, const float* __restrict__ bk,
    const float* __restrict__ bv,
    short* __restrict__ Qb, unsigned char* __restrict__ Kf8,
    unsigned char* __restrict__ Vf8)
{
    __shared__ short sm[2 * 16384];
    const int tid = threadIdx.x, lane = tid & 63, wid = tid >> 6;
    const int wm = wid >> 1, wn = wid & 1;
    const int r0 = blockIdx.x * 128;

    stage_tile(xb, r0, NN - 1, 128, 0, sm);
    #pragma unroll
    for (int m = 0; m < 3; ++m) {
        if (m) __syncthreads();
        stage_tile(Wt + m * 16384, 0, 127, 128, 0, sm + 16384);
        __syncthreads();
        f32x4 acc[4][4];
        #pragma unroll
        for (int i = 0; i < 4; ++i)
            #pragma unroll
            for (int j = 0; j < 4; ++j)
                acc[i][j] = (f32x4){0.f, 0.f, 0.f, 0.f};
        mfma_tile(sm, sm + 16384, wm, wn, lane, acc);

        const float* bias = m == 0 ? bq : (m == 1 ? bk : bv);
        #pragma unroll
        for (int fn = 0; fn < 4; ++fn) {
            int col = wn * 64 + fn * 16 + (lane & 15);
            float bc = bias[col];
            #pragma unroll
            for (int fm = 0; fm < 4; ++fm) {
                int rowb = r0 + wm * 64 + fm * 16 + (lane >> 4) * 4;
                #pragma unroll
                for (int rr = 0; rr < 4; ++rr) {
                    int gr = rowb + rr;
                    if (gr < NN) {
                        float v = acc[fm][fn][rr] + bc;
                        if (m == 0)
                            Qb[(size_t)gr * DM + col] = f2bf(v);
                        else if (m == 1)
                            Kf8[(size_t)gr * DM + col] = f2fp8(v);
                        else
                            Vf8[(size_t)gr * DM + col] = f2fp8(v);
                    }
                }
            }
        }
    }
}

// ---------------------------------------------------------------------------
// Wave-per-node fused attention, 16-edge chunks, fp8 K/V gathers (HW cvt).
__global__ __launch_bounds__(256) void k_attn_wave(
    const short* __restrict__ Qb, const unsigned char* __restrict__ Kf8,
    const unsigned char* __restrict__ Vf8, const int* __restrict__ col,
    const int* __restrict__ rowptr, const float* __restrict__ embn,
    short* __restrict__ aggb)
{
    const int lane = threadIdx.x & 63;
    const int n = blockIdx.x * 4 + (threadIdx.x >> 6);
    const int e0 = rowptr[n], e1 = rowptr[n + 1];
    const int s = lane >> 3, h = lane & 7;
    const int h2 = lane >> 3;

    float qf[16];
    {
        const bf16x8* qp = (const bf16x8*)(Qb + (size_t)n * DM + h * 16);
        bf16x8 q0 = qp[0], q1 = qp[1];
        #pragma unroll
        for (int j = 0; j < 8; ++j) { qf[j] = bf2f(q0[j]); qf[8 + j] = bf2f(q1[j]); }
    }
    const float embr = embn[(size_t)n * NH + h];

    float m = -INFINITY, l = 0.f, acc0 = 0.f, acc1 = 0.f;

    for (int c0 = e0; c0 < e1; c0 += 16) {
        int ea = c0 + s, eb = c0 + 8 + s;
        bool va = ea < e1, vb = eb < e1;
        int ca = col[va ? ea : e1 - 1];
        int cb = col[vb ? eb : e1 - 1];

        // K gathers: 16 fp8 values (16B) per edge-head
        int4 kwa = *(const int4*)(Kf8 + (size_t)ca * DM + h * 16);
        int4 kwb = *(const int4*)(Kf8 + (size_t)cb * DM + h * 16);
        float ema = embn[(size_t)ca * NH + h];
        float emB = embn[(size_t)cb * NH + h];

        // V preload (raw fp8 pairs), independent of scores
        int nv = e1 - c0; nv = nv > 16 ? 16 : nv;
        unsigned short vv[16];
        #pragma unroll
        for (int j = 0; j < 8; ++j) {
            int cj = __shfl(ca, j * 8);
            vv[j] = (j < nv) ? *(const unsigned short*)(Vf8 + (size_t)cj * DM + lane * 2) : 0;
        }
        #pragma unroll
        for (int j = 0; j < 8; ++j) {
            int cj = __shfl(cb, j * 8);
            vv[8 + j] = (8 + j < nv) ? *(const unsigned short*)(Vf8 + (size_t)cj * DM + lane * 2) : 0;
        }

        // decode + dot
        float da = 0.f, dbv = 0.f;
        {
            int ka[4] = {kwa.x, kwa.y, kwa.z, kwa.w};
            int kb[4] = {kwb.x, kwb.y, kwb.z, kwb.w};
            #pragma unroll
            for (int w = 0; w < 4; ++w) {
                f32x2 alo = __builtin_amdgcn_cvt_pk_f32_fp8(ka[w], false);
                f32x2 ahi = __builtin_amdgcn_cvt_pk_f32_fp8(ka[w], true);
                f32x2 blo = __builtin_amdgcn_cvt_pk_f32_fp8(kb[w], false);
                f32x2 bhi = __builtin_amdgcn_cvt_pk_f32_fp8(kb[w], true);
                da  += qf[w * 4 + 0] * alo[0] + qf[w * 4 + 1] * alo[1]
                     + qf[w * 4 + 2] * ahi[0] + qf[w * 4 + 3] * ahi[1];
                dbv += qf[w * 4 + 0] * blo[0] + qf[w * 4 + 1] * blo[1]
                     + qf[w * 4 + 2] * bhi[0] + qf[w * 4 + 3] * bhi[1];
            }
        }
        float sa = va ? da * 0.25f + embr + ema : -INFINITY;
        float sb = vb ? dbv * 0.25f + embr + emB : -INFINITY;

        float mc = fmaxf(sa, sb);
        mc = fmaxf(mc, __shfl_xor(mc, 8));
        mc = fmaxf(mc, __shfl_xor(mc, 16));
        mc = fmaxf(mc, __shfl_xor(mc, 32));
        float mn = fmaxf(m, mc);
        float f = __expf(m - mn);            // exp(-inf)=0 first chunk
        m = mn;
        float pa = __expf(sa - mn);
        float pb = __expf(sb - mn);
        float ps = pa + pb;
        ps += __shfl_xor(ps, 8);
        ps += __shfl_xor(ps, 16);
        ps += __shfl_xor(ps, 32);
        l = l * f + ps;

        float fr = __shfl(f, h2);
        acc0 *= fr; acc1 *= fr;
        #pragma unroll
        for (int j = 0; j < 8; ++j) {
            float pj = __shfl(pa, j * 8 + h2);
            f32x2 vd = __builtin_amdgcn_cvt_pk_f32_fp8((int)vv[j], false);
            acc0 += pj * vd[0];
            acc1 += pj * vd[1];
        }
        #pragma unroll
        for (int j = 0; j < 8; ++j) {
            float pj = __shfl(pb, j * 8 + h2);
            f32x2 vd = __builtin_amdgcn_cvt_pk_f32_fp8((int)vv[8 + j], false);
            acc0 += pj * vd[0];
            acc1 += pj * vd[1];
        }
    }
    float la = __shfl(l, h2);
    la = fmaxf(la, 1e-12f);
    unsigned o = ((unsigned)(unsigned short)f2bf(acc0 / la)) |
                 (((unsigned)(unsigned short)f2bf(acc1 / la)) << 16);
    *(unsigned*)(aggb + (size_t)n * DM + lane * 2) = o;
}

// ---------------------------------------------------------------------------
// agg@Wo + bo + x -> LN1 -> h (f32) and hb (bf16)
__global__ __launch_bounds__(256) void k_gemm_ln1(
    const short* __restrict__ aggb, const short* __restrict__ Wot,
    const float* __restrict__ bo, const float* __restrict__ x,
    const float* __restrict__ g, const float* __restrict__ b,
    float* __restrict__ h, short* __restrict__ hb)
{
    __shared__ union { short ab[2 * 16384]; float hs[128 * 129]; } u;
    __shared__ float mu[128], rsd[128];
    const int tid = threadIdx.x, lane = tid & 63, wid = tid >> 6;
    const int wm = wid >> 1, wn = wid & 1;
    const int r0 = blockIdx.x * 128;

    stage_tile(aggb, r0, NN - 1, 128, 0, u.ab);
    stage_tile(Wot, 0, 127, 128, 0, u.ab + 16384);
    __syncthreads();

    f32x4 acc[4][4];
    #pragma unroll
    for (int i = 0; i < 4; ++i)
        #pragma unroll
        for (int j = 0; j < 4; ++j) acc[i][j] = (f32x4){0.f, 0.f, 0.f, 0.f};
    mfma_tile(u.ab, u.ab + 16384, wm, wn, lane, acc);
    __syncthreads();

    #pragma unroll
    for (int fn = 0; fn < 4; ++fn) {
        int col = wn * 64 + fn * 16 + (lane & 15);
        float bc = bo[col];
        #pragma unroll
        for (int fm = 0; fm < 4; ++fm) {
            int rowb = wm * 64 + fm * 16 + (lane >> 4) * 4;
            #pragma unroll
            for (int rr = 0; rr < 4; ++rr) {
                int r_ = rowb + rr, gr = r0 + r_;
                float xr = (gr < NN) ? x[(size_t)gr * DM + col] : 0.f;
                u.hs[r_ * 129 + col] = acc[fm][fn][rr] + bc + xr;
            }
        }
    }
    __syncthreads();

    {
        int rrow = tid >> 1, half = tid & 1;
        float s = 0.f, q = 0.f;
        #pragma unroll 8
        for (int c = 0; c < 64; ++c) {
            float v = u.hs[rrow * 129 + half * 64 + c];
            s += v; q += v * v;
        }
        s += __shfl_xor(s, 1);
        q += __shfl_xor(q, 1);
        float m = s * (1.f / DM);
        float var = q * (1.f / DM) - m * m;
        if (half == 0) { mu[rrow] = m; rsd[rrow] = rsqrtf(var + 1e-5f); }
    }
    __syncthreads();

    for (int i = 0; i < 64; ++i) {
        int idx = i * 256 + tid;
        int rrow = idx >> 7, c = idx & 127;
        int gr = r0 + rrow;
        if (gr < NN) {
            float v = (u.hs[rrow * 129 + c] - mu[rrow]) * rsd[rrow] * g[c] + b[c];
            h[(size_t)gr * DM + c] = v;
            hb[(size_t)gr * DM + c] = f2bf(v);
        }
    }
}

// ---------------------------------------------------------------------------
// Fused FFN (R5 structure, best measured): gelu(hb@W1+b1)@W2 + b2 + h -> LN2.
// BM=64, 64KB dyn LDS: A[64x128] hb | B[128x128] weight chunk | C[64x128] ff.
__global__ __launch_bounds__(256) void k_ffn_fused(
    const short* __restrict__ hb, const short* __restrict__ Wt1,
    const float* __restrict__ b1, const short* __restrict__ Wt2,
    const float* __restrict__ b2, const float* __restrict__ h,
    const float* __restrict__ g, const float* __restrict__ bb,
    float* __restrict__ out)
{
    extern __shared__ char smraw[];
    short* A = (short*)smraw;          // 16 KB
    short* B = A + 8192;               // 32 KB
    short* C = B + 16384;              // 16 KB
    float* hs = (float*)smraw;         // overlay after gemms
    __shared__ float mu[64], rsd[64];

    const int tid = threadIdx.x, lane = tid & 63, wid = tid >> 6;
    const int wm = wid >> 1, wn = wid & 1;
    const int r0 = blockIdx.x * 64;

    f32x4 acc2[2][4];
    #pragma unroll
    for (int i = 0; i < 2; ++i)
        #pragma unroll
        for (int j = 0; j < 4; ++j) acc2[i][j] = (f32x4){0.f, 0.f, 0.f, 0.f};

    stage_tile64(hb, r0, NN - 1, 128, 0, A);

    for (int kc = 0; kc < 4; ++kc) {
        if (kc) __syncthreads();
        stage_tile(Wt1, kc * 128, FF - 1, 128, 0, B);
        __syncthreads();

        f32x4 accf[2][4];
        #pragma unroll
        for (int i = 0; i < 2; ++i)
            #pragma unroll
            for (int j = 0; j < 4; ++j) accf[i][j] = (f32x4){0.f, 0.f, 0.f, 0.f};
        mfma_tile64(A, B, wm, wn, lane, accf);

        #pragma unroll
        for (int fn = 0; fn < 4; ++fn) {
            int nloc = wn * 64 + fn * 16 + (lane & 15);
            float bc = b1[kc * 128 + nloc];
            int slot = nloc >> 3;
            #pragma unroll
            for (int fm = 0; fm < 2; ++fm) {
                int rowb = wm * 32 + fm * 16 + (lane >> 4) * 4;
                #pragma unroll
                for (int rr = 0; rr < 4; ++rr) {
                    int row = rowb + rr;
                    float v = gelu_f(accf[fm][fn][rr] + bc);
                    C[row * 128 + (((slot ^ (row & 7)) << 3) | (nloc & 7))] = f2bf(v);
                }
            }
        }
        __syncthreads();
        stage_tile(Wt2, 0, 127, FF, kc * 128, B);
        __syncthreads();
        mfma_tile64(C, B, wm, wn, lane, acc2);
    }
    __syncthreads();

    #pragma unroll
    for (int fn = 0; fn < 4; ++fn) {
        int col = wn * 64 + fn * 16 + (lane & 15);
        float bc = b2[col];
        #pragma unroll
        for (int fm = 0; fm < 2; ++fm) {
            int rowb = wm * 32 + fm * 16 + (lane >> 4) * 4;
            #pragma unroll
            for (int rr = 0; rr < 4; ++rr) {
                int r_ = rowb + rr, gr = r0 + r_;
                float hr = (gr < NN) ? h[(size_t)gr * DM + col] : 0.f;
                hs[r_ * 129 + col] = acc2[fm][fn][rr] + bc + hr;
            }
        }
    }
    __syncthreads();

    {
        int rrow = tid >> 2, q = tid & 3;
        float s = 0.f, qq = 0.f;
        #pragma unroll 8
        for (int c = 0; c < 32; ++c) {
            float v = hs[rrow * 129 + q * 32 + c];
            s += v; qq += v * v;
        }
        s += __shfl_xor(s, 1);  qq += __shfl_xor(qq, 1);
        s += __shfl_xor(s, 2);  qq += __shfl_xor(qq, 2);
        float m = s * (1.f / DM);
        float var = qq * (1.f / DM) - m * m;
        if (q == 0) { mu[rrow] = m; rsd[rrow] = rsqrtf(var + 1e-5f); }
    }
    __syncthreads();

    for (int i = 0; i < 32; ++i) {
        int idx = i * 256 + tid;
        int rrow = idx >> 7, c = idx & 127;
        int gr = r0 + rrow;
        if (gr < NN)
            out[(size_t)gr * DM + c] =
                (hs[rrow * 129 + c] - mu[rrow]) * rsd[rrow] * g[c] + bb[c];
    }
}

// ---------------------------------------------------------------------------
extern "C" void kernel_launch(void* const* d_in, const int* in_sizes, int n_in,
                              void* d_out, int out_size, void* d_ws, size_t ws_size,
                              hipStream_t stream) {
    const float* x   = (const float*)d_in[0];
    const int* row   = (const int*)d_in[1];
    const int* col   = (const int*)d_in[2];
    const int* db    = (const int*)d_in[3];
    const float* Wq  = (const float*)d_in[4];
    const float* bq  = (const float*)d_in[5];
    const float* Wk  = (const float*)d_in[6];
    const float* bk  = (const float*)d_in[7];
    const float* Wv  = (const float*)d_in[8];
    const float* bv  = (const float*)d_in[9];
    const float* Wo  = (const float*)d_in[10];
    const float* bo  = (const float*)d_in[11];
    const float* emb = (const float*)d_in[12];
    const float* g1  = (const float*)d_in[13];
    const float* b1n = (const float*)d_in[14];
    const float* g2  = (const float*)d_in[15];
    const float* b2n = (const float*)d_in[16];
    const float* W1  = (const float*)d_in[17];
    const float* b1  = (const float*)d_in[18];
    const float* W2  = (const float*)d_in[19];
    const float* b2  = (const float*)d_in[20];

    char* W = (char*)d_ws;
    float* embn          = (float*)(W + 0);          // 1.6 MB
    unsigned char* Kf8   = (unsigned char*)(W + 1600000);   // 6.4 MB
    unsigned char* Vf8   = (unsigned char*)(W + 8000000);   // 6.4 MB
    short* aggb   = (short*)(W + 25600000);
    short* xb     = (short*)(W + 38400000);
    short* Qb     = (short*)(W + 51200000);          // 12.8 MB
    float* h      = (float*)(W + 51200000);          // overlay (Qb dead post-attn)
    short* hb     = (short*)(W + 76800000);
    short* wts    = (short*)(W + 89600000);
    int* rowptr   = (int*)(W + 89993216);

    k_prep<<<PB_TOT, 256, 0, stream>>>(x, xb, Wq, Wk, Wv, Wo, W1, W2, wts,
                                       row, rowptr, db, emb, embn);
    k_gemm_qkv<<<NBLK, 256, 0, stream>>>(xb, wts, bq, bk, bv, Qb, Kf8, Vf8);
    k_attn_wave<<<NN / 4, 256, 0, stream>>>(Qb, Kf8, Vf8, col, rowptr, embn, aggb);
    k_gemm_ln1<<<NBLK, 256, 0, stream>>>(aggb, wts + 49152, bo, x, g1, b1n, h, hb);
    k_ffn_fused<<<NBLK64, 256, 65536, stream>>>(hb, wts + 65536, b1,
                                                wts + 131072, b2, h, g2, b2n,
                                                (float*)d_out);
}

// Round 12
// 203.878 us; speedup vs baseline: 1.2392x; 1.0226x over previous
//
#include <hip/hip_runtime.h>
#include <math.h>

#define NN 50000
#define NE 800000
#define DM 128
#define NH 8
#define FF 512
#define NBLK 391    // ceil(50000/128)
#define NBLK64 782  // ceil(50000/64)

// merged prep kernel block ranges
#define PB_X    6250          // x->bf16 blocks
#define PB_WT   192           // weight transpose blocks
#define PB_RP   196           // rowptr blocks
#define PB_EMB  1563          // embn blocks
#define PB_TOT  (PB_X + PB_WT + PB_RP + PB_EMB)

typedef __attribute__((ext_vector_type(8))) short bf16x8;
typedef __attribute__((ext_vector_type(4))) float f32x4;
typedef __attribute__((ext_vector_type(2))) float f32x2;

__device__ __forceinline__ short f2bf(float f) {
    union { float f; unsigned u; } v; v.f = f;
    unsigned r = v.u + 0x7fff + ((v.u >> 16) & 1);
    return (short)(r >> 16);
}
__device__ __forceinline__ float bf2f(short s) {
    union { unsigned u; float f; } v; v.u = ((unsigned)(unsigned short)s) << 16;
    return v.f;
}
// fp8 e4m3 encode via HW cvt (RNE)
__device__ __forceinline__ unsigned char f2fp8(float f) {
    int p = __builtin_amdgcn_cvt_pk_fp8_f32(f, f, 0, false);
    return (unsigned char)(p & 0xff);
}

// fast gelu (tanh form; |err|~2e-4 in our ff range, ~1e-4 after W2)
__device__ __forceinline__ float gelu_f(float x) {
    float u = x * (0.7978845608f + 0.0356774081f * x * x);
    float t = 1.f - 2.f / (__expf(2.f * u) + 1.f);
    return 0.5f * x * (1.f + t);
}

// ---------------------------------------------------------------------------
__device__ __forceinline__ void gload16(const void* g, void* l) {
    __builtin_amdgcn_global_load_lds(
        (const __attribute__((address_space(1))) void*)g,
        (__attribute__((address_space(3))) void*)l, 16, 0, 0);
}

// Stage 128x128 bf16 tile with XOR swizzle (inverse-swizzled global source +
// linear LDS dest; reads apply same XOR — rule #21).
__device__ __forceinline__ void stage_tile(const short* __restrict__ src, int row0,
                                           int maxrow, int ld, int col0,
                                           short* sm) {
    const int tid = threadIdx.x;
    const int w = tid >> 6, l = tid & 63;
    const int p = l & 15;
    #pragma unroll
    for (int j = 0; j < 8; ++j) {
        int lr = w * 32 + j * 4 + (l >> 4);
        int gr = row0 + lr; gr = gr > maxrow ? maxrow : gr;
        int s = p ^ (lr & 7);
        const short* g = src + (size_t)gr * ld + col0 + s * 8;
        gload16(g, sm + (w * 32 + j * 4) * 128);
    }
}

// Stage R x 128B fp8 tile with 16B-granule XOR swizzle (same rule #21 trick:
// linear LDS dest, inverse-swizzled global source; reads apply same XOR).
// Each wave covers 8 rows per gload16 call.
template <int R>
__device__ __forceinline__ void stage_tile_f8(const unsigned char* __restrict__ src,
                                              int row0, int maxrow, int ld, int col0,
                                              unsigned char* sm) {
    const int tid = threadIdx.x;
    const int w = tid >> 6, l = tid & 63;
    const int p = l & 7;                 // physical 16B granule this lane fills
    const int rsub = l >> 3;             // row within the 8-row span
    #pragma unroll
    for (int j = 0; j < (R >> 5); ++j) {
        int lr = w * (R >> 2) + j * 8 + rsub;
        int gr = row0 + lr; gr = gr > maxrow ? maxrow : gr;
        int g = p ^ (lr & 7);
        const unsigned char* gp = src + (size_t)gr * ld + col0 + g * 16;
        gload16(gp, sm + (w * (R >> 2) + j * 8) * 128);
    }
}

__device__ __forceinline__ bf16x8 frag_ld(const short* sm, int outer, int slot) {
    return *(const bf16x8*)(sm + outer * 128 + ((slot ^ (outer & 7)) << 3));
}

// fp8 frag: 8 bytes at 8B-slot `slot` of row `outer` (16B-granule swizzle)
__device__ __forceinline__ long frag_ld_f8(const unsigned char* sm, int outer, int slot) {
    return *(const long*)(sm + outer * 128 +
                          (((slot >> 1) ^ (outer & 7)) << 4) + ((slot & 1) << 3));
}

__device__ __forceinline__ void mfma_tile(const short* sA, const short* sB,
                                          int wm, int wn, int lane,
                                          f32x4 acc[4][4]) {
    const int l15 = lane & 15, l4 = lane >> 4;
    #pragma unroll
    for (int ks = 0; ks < 4; ++ks) {
        bf16x8 a[4], b[4];
        int slot = ks * 4 + l4;
        #pragma unroll
        for (int f = 0; f < 4; ++f) a[f] = frag_ld(sA, wm * 64 + f * 16 + l15, slot);
        #pragma unroll
        for (int f = 0; f < 4; ++f) b[f] = frag_ld(sB, wn * 64 + f * 16 + l15, slot);
        #pragma unroll
        for (int fm = 0; fm < 4; ++fm)
            #pragma unroll
            for (int fn = 0; fn < 4; ++fn)
                acc[fm][fn] = __builtin_amdgcn_mfma_f32_16x16x32_bf16(
                    a[fm], b[fn], acc[fm][fn], 0, 0, 0);
    }
}

// fp8 64x128x128: A-op 64 rows (2x32 over wm), B-op 128 rows (2x64 over wn)
__device__ __forceinline__ void mfma_tile64_f8(const unsigned char* sA,
                                               const unsigned char* sB,
                                               int wm, int wn, int lane,
                                               f32x4 acc[2][4]) {
    const int l15 = lane & 15, l4 = lane >> 4;
    #pragma unroll
    for (int ks = 0; ks < 4; ++ks) {
        long a[2], b[4];
        int slot = ks * 4 + l4;
        #pragma unroll
        for (int f = 0; f < 2; ++f) a[f] = frag_ld_f8(sA, wm * 32 + f * 16 + l15, slot);
        #pragma unroll
        for (int f = 0; f < 4; ++f) b[f] = frag_ld_f8(sB, wn * 64 + f * 16 + l15, slot);
        #pragma unroll
        for (int fm = 0; fm < 2; ++fm)
            #pragma unroll
            for (int fn = 0; fn < 4; ++fn)
                acc[fm][fn] = __builtin_amdgcn_mfma_f32_16x16x32_fp8_fp8(
                    a[fm], b[fn], acc[fm][fn], 0, 0, 0);
    }
}

// ---------------------------------------------------------------------------
// Merged prep: x->bf16 | QKV/Wo bf16 + W1/W2 fp8(x16) transposes | rowptr | embn.
__global__ __launch_bounds__(256) void k_prep(
    const float* __restrict__ x, short* __restrict__ xb,
    const float* __restrict__ Wq, const float* __restrict__ Wk,
    const float* __restrict__ Wv, const float* __restrict__ Wo,
    const float* __restrict__ W1, const float* __restrict__ W2,
    short* __restrict__ wts,
    unsigned char* __restrict__ w1f8, unsigned char* __restrict__ w2f8,
    const int* __restrict__ row, int* __restrict__ rowptr,
    const int* __restrict__ db, const float* __restrict__ emb,
    float* __restrict__ embn)
{
    int bid = blockIdx.x;
    const int tid = threadIdx.x;

    if (bid < PB_X) {
        int i = bid * 256 + tid;
        if (i < NN * DM / 4) {
            float4 v = ((const float4*)x)[i];
            ((short4*)xb)[i] = make_short4(f2bf(v.x), f2bf(v.y), f2bf(v.z), f2bf(v.w));
        }
        return;
    }
    bid -= PB_X;
    if (bid < PB_WT) {
        const float* W; int K, N, bx, by;
        short* Wt = nullptr; unsigned char* Wf8 = nullptr;
        if (bid < 64) {
            int wsel = bid >> 4, rel = bid & 15;
            W = wsel == 0 ? Wq : wsel == 1 ? Wk : wsel == 2 ? Wv : Wo;
            Wt = wts + wsel * 16384; K = 128; N = 128; bx = rel & 3; by = rel >> 2;
        } else if (bid < 128) {
            int rel = bid - 64;
            W = W1; Wf8 = w1f8; K = 128; N = 512; bx = rel & 15; by = rel >> 4;
        } else {
            int rel = bid - 128;
            W = W2; Wf8 = w2f8; K = 512; N = 128; bx = rel & 3; by = rel >> 2;
        }
        __shared__ float t[32][33];
        int n0 = bx * 32, k0 = by * 32;
        int r = tid >> 3, c4 = (tid & 7) * 4;
        float4 v = *(const float4*)(W + (size_t)(k0 + r) * N + n0 + c4);
        t[r][c4 + 0] = v.x; t[r][c4 + 1] = v.y; t[r][c4 + 2] = v.z; t[r][c4 + 3] = v.w;
        __syncthreads();
        if (Wt) {
            short4 o = make_short4(f2bf(t[c4 + 0][r]), f2bf(t[c4 + 1][r]),
                                   f2bf(t[c4 + 2][r]), f2bf(t[c4 + 3][r]));
            *(short4*)(Wt + (size_t)(n0 + r) * K + k0 + c4) = o;
        } else {
            // fp8, scaled x16 so sigma=0.02 weights land in e4m3 normal range
            uchar4 o = make_uchar4(f2fp8(16.f * t[c4 + 0][r]), f2fp8(16.f * t[c4 + 1][r]),
                                   f2fp8(16.f * t[c4 + 2][r]), f2fp8(16.f * t[c4 + 3][r]));
            *(uchar4*)(Wf8 + (size_t)(n0 + r) * K + k0 + c4) = o;
        }
        return;
    }
    bid -= PB_WT;
    if (bid < PB_RP) {
        int n = bid * 256 + tid;
        if (n > NN) return;
        int lo = 0, hi = NE;
        while (lo < hi) {
            int mid = (lo + hi) >> 1;
            if (row[mid] < n) lo = mid + 1; else hi = mid;
        }
        rowptr[n] = lo;
        return;
    }
    bid -= PB_RP;
    {
        int i = bid * 256 + tid;
        if (i < NN * NH) embn[i] = emb[db[i >> 3] * NH + (i & 7)];
    }
}

// ---------------------------------------------------------------------------
// QKV: Q out as bf16; K and V out as fp8 e4m3 (halves attn gather traffic).
__global__ __launch_bounds__(256) void k_gemm_qkv(
    const short* __restrict__ xb, const short* __restrict__ Wt,
    const float* __restrict__ bq, const float* __restrict__ bk,
    const float* __restrict__ bv,
    short* __restrict__ Qb, unsigned char* __restrict__ Kf8,
    unsigned char* __restrict__ Vf8)
{
    __shared__ short sm[2 * 16384];
    const int tid = threadIdx.x, lane = tid & 63, wid = tid >> 6;
    const int wm = wid >> 1, wn = wid & 1;
    const int r0 = blockIdx.x * 128;

    stage_tile(xb, r0, NN - 1, 128, 0, sm);
    #pragma unroll
    for (int m = 0; m < 3; ++m) {
        if (m) __syncthreads();
        stage_tile(Wt + m * 16384, 0, 127, 128, 0, sm + 16384);
        __syncthreads();
        f32x4 acc[4][4];
        #pragma unroll
        for (int i = 0; i < 4; ++i)
            #pragma unroll
            for (int j = 0; j < 4; ++j)
                acc[i][j] = (f32x4){0.f, 0.f, 0.f, 0.f};
        mfma_tile(sm, sm + 16384, wm, wn, lane, acc);

        const float* bias = m == 0 ? bq : (m == 1 ? bk : bv);
        #pragma unroll
        for (int fn = 0; fn < 4; ++fn) {
            int col = wn * 64 + fn * 16 + (lane & 15);
            float bc = bias[col];
            #pragma unroll
            for (int fm = 0; fm < 4; ++fm) {
                int rowb = r0 + wm * 64 + fm * 16 + (lane >> 4) * 4;
                #pragma unroll
                for (int rr = 0; rr < 4; ++rr) {
                    int gr = rowb + rr;
                    if (gr < NN) {
                        float v = acc[fm][fn][rr] + bc;
                        if (m == 0)
                            Qb[(size_t)gr * DM + col] = f2bf(v);
                        else if (m == 1)
                            Kf8[(size_t)gr * DM + col] = f2fp8(v);
                        else
                            Vf8[(size_t)gr * DM + col] = f2fp8(v);
                    }
                }
            }
        }
    }
}

// ---------------------------------------------------------------------------
// Wave-per-node fused attention, 16-edge chunks, fp8 K/V gathers (HW cvt).
__global__ __launch_bounds__(256) void k_attn_wave(
    const short* __restrict__ Qb, const unsigned char* __restrict__ Kf8,
    const unsigned char* __restrict__ Vf8, const int* __restrict__ col,
    const int* __restrict__ rowptr, const float* __restrict__ embn,
    short* __restrict__ aggb)
{
    const int lane = threadIdx.x & 63;
    const int n = blockIdx.x * 4 + (threadIdx.x >> 6);
    const int e0 = rowptr[n], e1 = rowptr[n + 1];
    const int s = lane >> 3, h = lane & 7;
    const int h2 = lane >> 3;

    float qf[16];
    {
        const bf16x8* qp = (const bf16x8*)(Qb + (size_t)n * DM + h * 16);
        bf16x8 q0 = qp[0], q1 = qp[1];
        #pragma unroll
        for (int j = 0; j < 8; ++j) { qf[j] = bf2f(q0[j]); qf[8 + j] = bf2f(q1[j]); }
    }
    const float embr = embn[(size_t)n * NH + h];

    float m = -INFINITY, l = 0.f, acc0 = 0.f, acc1 = 0.f;

    for (int c0 = e0; c0 < e1; c0 += 16) {
        int ea = c0 + s, eb = c0 + 8 + s;
        bool va = ea < e1, vb = eb < e1;
        int ca = col[va ? ea : e1 - 1];
        int cb = col[vb ? eb : e1 - 1];

        // K gathers: 16 fp8 values (16B) per edge-head
        int4 kwa = *(const int4*)(Kf8 + (size_t)ca * DM + h * 16);
        int4 kwb = *(const int4*)(Kf8 + (size_t)cb * DM + h * 16);
        float ema = embn[(size_t)ca * NH + h];
        float emB = embn[(size_t)cb * NH + h];

        // V preload (raw fp8 pairs), independent of scores
        int nv = e1 - c0; nv = nv > 16 ? 16 : nv;
        unsigned short vv[16];
        #pragma unroll
        for (int j = 0; j < 8; ++j) {
            int cj = __shfl(ca, j * 8);
            vv[j] = (j < nv) ? *(const unsigned short*)(Vf8 + (size_t)cj * DM + lane * 2) : 0;
        }
        #pragma unroll
        for (int j = 0; j < 8; ++j) {
            int cj = __shfl(cb, j * 8);
            vv[8 + j] = (8 + j < nv) ? *(const unsigned short*)(Vf8 + (size_t)cj * DM + lane * 2) : 0;
        }

        // decode + dot
        float da = 0.f, dbv = 0.f;
        {
            int ka[4] = {kwa.x, kwa.y, kwa.z, kwa.w};
            int kb[4] = {kwb.x, kwb.y, kwb.z, kwb.w};
            #pragma unroll
            for (int w = 0; w < 4; ++w) {
                f32x2 alo = __builtin_amdgcn_cvt_pk_f32_fp8(ka[w], false);
                f32x2 ahi = __builtin_amdgcn_cvt_pk_f32_fp8(ka[w], true);
                f32x2 blo = __builtin_amdgcn_cvt_pk_f32_fp8(kb[w], false);
                f32x2 bhi = __builtin_amdgcn_cvt_pk_f32_fp8(kb[w], true);
                da  += qf[w * 4 + 0] * alo[0] + qf[w * 4 + 1] * alo[1]
                     + qf[w * 4 + 2] * ahi[0] + qf[w * 4 + 3] * ahi[1];
                dbv += qf[w * 4 + 0] * blo[0] + qf[w * 4 + 1] * blo[1]
                     + qf[w * 4 + 2] * bhi[0] + qf[w * 4 + 3] * bhi[1];
            }
        }
        float sa = va ? da * 0.25f + embr + ema : -INFINITY;
        float sb = vb ? dbv * 0.25f + embr + emB : -INFINITY;

        float mc = fmaxf(sa, sb);
        mc = fmaxf(mc, __shfl_xor(mc, 8));
        mc = fmaxf(mc, __shfl_xor(mc, 16));
        mc = fmaxf(mc, __shfl_xor(mc, 32));
        float mn = fmaxf(m, mc);
        float f = __expf(m - mn);            // exp(-inf)=0 first chunk
        m = mn;
        float pa = __expf(sa - mn);
        float pb = __expf(sb - mn);
        float ps = pa + pb;
        ps += __shfl_xor(ps, 8);
        ps += __shfl_xor(ps, 16);
        ps += __shfl_xor(ps, 32);
        l = l * f + ps;

        float fr = __shfl(f, h2);
        acc0 *= fr; acc1 *= fr;
        #pragma unroll
        for (int j = 0; j < 8; ++j) {
            float pj = __shfl(pa, j * 8 + h2);
            f32x2 vd = __builtin_amdgcn_cvt_pk_f32_fp8((int)vv[j], false);
            acc0 += pj * vd[0];
            acc1 += pj * vd[1];
        }
        #pragma unroll
        for (int j = 0; j < 8; ++j) {
            float pj = __shfl(pb, j * 8 + h2);
            f32x2 vd = __builtin_amdgcn_cvt_pk_f32_fp8((int)vv[8 + j], false);
            acc0 += pj * vd[0];
            acc1 += pj * vd[1];
        }
    }
    float la = __shfl(l, h2);
    la = fmaxf(la, 1e-12f);
    unsigned o = ((unsigned)(unsigned short)f2bf(acc0 / la)) |
                 (((unsigned)(unsigned short)f2bf(acc1 / la)) << 16);
    *(unsigned*)(aggb + (size_t)n * DM + lane * 2) = o;
}

// ---------------------------------------------------------------------------
// agg@Wo + bo + x -> LN1 -> h (f32) and hb8 (fp8, FFN GEMM input)
__global__ __launch_bounds__(256) void k_gemm_ln1(
    const short* __restrict__ aggb, const short* __restrict__ Wot,
    const float* __restrict__ bo, const float* __restrict__ x,
    const float* __restrict__ g, const float* __restrict__ b,
    float* __restrict__ h, unsigned char* __restrict__ hb8)
{
    __shared__ union { short ab[2 * 16384]; float hs[128 * 129]; } u;
    __shared__ float mu[128], rsd[128];
    const int tid = threadIdx.x, lane = tid & 63, wid = tid >> 6;
    const int wm = wid >> 1, wn = wid & 1;
    const int r0 = blockIdx.x * 128;

    stage_tile(aggb, r0, NN - 1, 128, 0, u.ab);
    stage_tile(Wot, 0, 127, 128, 0, u.ab + 16384);
    __syncthreads();

    f32x4 acc[4][4];
    #pragma unroll
    for (int i = 0; i < 4; ++i)
        #pragma unroll
        for (int j = 0; j < 4; ++j) acc[i][j] = (f32x4){0.f, 0.f, 0.f, 0.f};
    mfma_tile(u.ab, u.ab + 16384, wm, wn, lane, acc);
    __syncthreads();

    #pragma unroll
    for (int fn = 0; fn < 4; ++fn) {
        int col = wn * 64 + fn * 16 + (lane & 15);
        float bc = bo[col];
        #pragma unroll
        for (int fm = 0; fm < 4; ++fm) {
            int rowb = wm * 64 + fm * 16 + (lane >> 4) * 4;
            #pragma unroll
            for (int rr = 0; rr < 4; ++rr) {
                int r_ = rowb + rr, gr = r0 + r_;
                float xr = (gr < NN) ? x[(size_t)gr * DM + col] : 0.f;
                u.hs[r_ * 129 + col] = acc[fm][fn][rr] + bc + xr;
            }
        }
    }
    __syncthreads();

    {
        int rrow = tid >> 1, half = tid & 1;
        float s = 0.f, q = 0.f;
        #pragma unroll 8
        for (int c = 0; c < 64; ++c) {
            float v = u.hs[rrow * 129 + half * 64 + c];
            s += v; q += v * v;
        }
        s += __shfl_xor(s, 1);
        q += __shfl_xor(q, 1);
        float m = s * (1.f / DM);
        float var = q * (1.f / DM) - m * m;
        if (half == 0) { mu[rrow] = m; rsd[rrow] = rsqrtf(var + 1e-5f); }
    }
    __syncthreads();

    for (int i = 0; i < 64; ++i) {
        int idx = i * 256 + tid;
        int rrow = idx >> 7, c = idx & 127;
        int gr = r0 + rrow;
        if (gr < NN) {
            float v = (u.hs[rrow * 129 + c] - mu[rrow]) * rsd[rrow] * g[c] + b[c];
            h[(size_t)gr * DM + c] = v;
            hb8[(size_t)gr * DM + c] = f2fp8(v);
        }
    }
}

// ---------------------------------------------------------------------------
// Fused FFN, fp8 data path (R5 structure; dtypes shrunk):
//   A[64x128] hb8 (8K) | B[128x128] fp8 weight chunk (16K) | C[64x128] 16*gelu (8K)
//   LDS 33 KB -> 4 blocks/CU (was 64 KB -> 2). Weights scaled x16 at prep;
//   unscale folds into epilogues (x1/16 pre-gelu, x1/256 pre-b2).
__global__ __launch_bounds__(256) void k_ffn_fused(
    const unsigned char* __restrict__ hb8, const unsigned char* __restrict__ W1f8,
    const float* __restrict__ b1, const unsigned char* __restrict__ W2f8,
    const float* __restrict__ b2, const float* __restrict__ h,
    const float* __restrict__ g, const float* __restrict__ bb,
    float* __restrict__ out)
{
    extern __shared__ char smraw[];
    unsigned char* A = (unsigned char*)smraw;   // 8 KB
    unsigned char* B = A + 8192;                // 16 KB
    unsigned char* C = B + 16384;               // 8 KB
    float* hs = (float*)smraw;                  // overlay after gemms (33 KB)
    __shared__ float mu[64], rsd[64];

    const int tid = threadIdx.x, lane = tid & 63, wid = tid >> 6;
    const int wm = wid >> 1, wn = wid & 1;
    const int l15 = lane & 15, l4 = lane >> 4;
    const int r0 = blockIdx.x * 64;

    f32x4 acc2[2][4];
    #pragma unroll
    for (int i = 0; i < 2; ++i)
        #pragma unroll
        for (int j = 0; j < 4; ++j) acc2[i][j] = (f32x4){0.f, 0.f, 0.f, 0.f};

    stage_tile_f8<64>(hb8, r0, NN - 1, 128, 0, A);

    for (int kc = 0; kc < 4; ++kc) {
        if (kc) __syncthreads();
        stage_tile_f8<128>(W1f8, kc * 128, FF - 1, 128, 0, B);
        __syncthreads();

        f32x4 accf[2][4];
        #pragma unroll
        for (int i = 0; i < 2; ++i)
            #pragma unroll
            for (int j = 0; j < 4; ++j) accf[i][j] = (f32x4){0.f, 0.f, 0.f, 0.f};
        mfma_tile64_f8(A, B, wm, wn, lane, accf);

        // gelu -> C (fp8, x16), swizzled byte stores
        #pragma unroll
        for (int fn = 0; fn < 4; ++fn) {
            int nloc = wn * 64 + fn * 16 + l15;
            float bc = b1[kc * 128 + nloc];
            #pragma unroll
            for (int fm = 0; fm < 2; ++fm) {
                int rowb = wm * 32 + fm * 16 + l4 * 4;
                #pragma unroll
                for (int rr = 0; rr < 4; ++rr) {
                    int row = rowb + rr;
                    float v = 16.f * gelu_f(accf[fm][fn][rr] * 0.0625f + bc);
                    C[row * 128 + ((((nloc >> 4) ^ (row & 7)) << 4) | (nloc & 15))]
                        = f2fp8(v);
                }
            }
        }
        __syncthreads();
        stage_tile_f8<128>(W2f8, 0, 127, 512, kc * 128, B);
        __syncthreads();
        mfma_tile64_f8(C, B, wm, wn, lane, acc2);
    }
    __syncthreads();                 // all C/B reads done; overlay hs

    #pragma unroll
    for (int fn = 0; fn < 4; ++fn) {
        int col = wn * 64 + fn * 16 + l15;
        float bc = b2[col];
        #pragma unroll
        for (int fm = 0; fm < 2; ++fm) {
            int rowb = wm * 32 + fm * 16 + l4 * 4;
            #pragma unroll
            for (int rr = 0; rr < 4; ++rr) {
                int r_ = rowb + rr, gr = r0 + r_;
                float hr = (gr < NN) ? h[(size_t)gr * DM + col] : 0.f;
                hs[r_ * 129 + col] = acc2[fm][fn][rr] * (1.f / 256.f) + bc + hr;
            }
        }
    }
    __syncthreads();

    {
        int rrow = tid >> 2, q = tid & 3;
        float s = 0.f, qq = 0.f;
        #pragma unroll 8
        for (int c = 0; c < 32; ++c) {
            float v = hs[rrow * 129 + q * 32 + c];
            s += v; qq += v * v;
        }
        s += __shfl_xor(s, 1);  qq += __shfl_xor(qq, 1);
        s += __shfl_xor(s, 2);  qq += __shfl_xor(qq, 2);
        float m = s * (1.f / DM);
        float var = qq * (1.f / DM) - m * m;
        if (q == 0) { mu[rrow] = m; rsd[rrow] = rsqrtf(var + 1e-5f); }
    }
    __syncthreads();

    for (int i = 0; i < 32; ++i) {
        int idx = i * 256 + tid;
        int rrow = idx >> 7, c = idx & 127;
        int gr = r0 + rrow;
        if (gr < NN)
            out[(size_t)gr * DM + c] =
                (hs[rrow * 129 + c] - mu[rrow]) * rsd[rrow] * g[c] + bb[c];
    }
}

// ---------------------------------------------------------------------------
extern "C" void kernel_launch(void* const* d_in, const int* in_sizes, int n_in,
                              void* d_out, int out_size, void* d_ws, size_t ws_size,
                              hipStream_t stream) {
    const float* x   = (const float*)d_in[0];
    const int* row   = (const int*)d_in[1];
    const int* col   = (const int*)d_in[2];
    const int* db    = (const int*)d_in[3];
    const float* Wq  = (const float*)d_in[4];
    const float* bq  = (const float*)d_in[5];
    const float* Wk  = (const float*)d_in[6];
    const float* bk  = (const float*)d_in[7];
    const float* Wv  = (const float*)d_in[8];
    const float* bv  = (const float*)d_in[9];
    const float* Wo  = (const float*)d_in[10];
    const float* bo  = (const float*)d_in[11];
    const float* emb = (const float*)d_in[12];
    const float* g1  = (const float*)d_in[13];
    const float* b1n = (const float*)d_in[14];
    const float* g2  = (const float*)d_in[15];
    const float* b2n = (const float*)d_in[16];
    const float* W1  = (const float*)d_in[17];
    const float* b1  = (const float*)d_in[18];
    const float* W2  = (const float*)d_in[19];
    const float* b2  = (const float*)d_in[20];

    char* W = (char*)d_ws;
    float* embn          = (float*)(W + 0);                  // 1.6 MB
    unsigned char* Kf8   = (unsigned char*)(W + 1600000);    // 6.4 MB
    unsigned char* Vf8   = (unsigned char*)(W + 8000000);    // 6.4 MB
    short* aggb   = (short*)(W + 25600000);                  // 12.8 MB
    short* xb     = (short*)(W + 38400000);                  // 12.8 MB
    short* Qb     = (short*)(W + 51200000);                  // 12.8 MB
    float* h      = (float*)(W + 51200000);                  // overlay (Qb dead post-attn)
    unsigned char* hb8 = (unsigned char*)(W + 76800000);     // 6.4 MB
    short* wts    = (short*)(W + 89600000);                  // 131,072 B (QKV+Wo bf16)
    unsigned char* w1f8 = (unsigned char*)(W + 89731072);    // 65,536 B
    unsigned char* w2f8 = (unsigned char*)(W + 89796608);    // 65,536 B
    int* rowptr   = (int*)(W + 89862144);                    // 200,004 B

    k_prep<<<PB_TOT, 256, 0, stream>>>(x, xb, Wq, Wk, Wv, Wo, W1, W2, wts,
                                       w1f8, w2f8, row, rowptr, db, emb, embn);
    k_gemm_qkv<<<NBLK, 256, 0, stream>>>(xb, wts, bq, bk, bv, Qb, Kf8, Vf8);
    k_attn_wave<<<NN / 4, 256, 0, stream>>>(Qb, Kf8, Vf8, col, rowptr, embn, aggb);
    k_gemm_ln1<<<NBLK, 256, 0, stream>>>(aggb, wts + 49152, bo, x, g1, b1n, h, hb8);
    k_ffn_fused<<<NBLK64, 256, 33024, stream>>>(hb8, w1f8, b1, w2f8, b2, h,
                                                g2, b2n, (float*)d_out);
}